// Round 9
// baseline (974.895 us; speedup 1.0000x reference)
//
#include <hip/hip_runtime.h>
#include <hip/hip_bf16.h>
#include <cstdint>
#include <cstddef>

#define D 128

typedef __hip_bfloat16 bf16;
typedef __attribute__((ext_vector_type(8))) short short8v;   // 8 bf16 (4 VGPR)
typedef __attribute__((ext_vector_type(4))) float f32x4;     // MFMA 16x16 acc

// ---------- typed load/store helpers ----------
__device__ inline float ld1(const float* p) { return *p; }
__device__ inline float ld1(const bf16* p) { return __bfloat162float(*p); }
__device__ inline float2 ld2(const float* p) { return *(const float2*)p; }
__device__ inline float2 ld2(const bf16* p) {
  __hip_bfloat162 v = *(const __hip_bfloat162*)p;
  float2 r; r.x = __bfloat162float(v.x); r.y = __bfloat162float(v.y); return r;
}
__device__ inline void st2(float* p, float a, float b) {
  float2 v; v.x = a; v.y = b; *(float2*)p = v;
}
__device__ inline void st2(bf16* p, float a, float b) {
  __hip_bfloat162 v; v.x = __float2bfloat16(a); v.y = __float2bfloat16(b);
  *(__hip_bfloat162*)p = v;
}

// bf16 bit helpers (RNE)
__device__ inline short f2bf(float x) {
  uint32_t u = __builtin_bit_cast(uint32_t, x);
  uint32_t r = (u + 0x7FFFu + ((u >> 16) & 1u)) >> 16;
  return (short)(uint16_t)r;
}
__device__ inline float bf2f(short s) {
  uint32_t u = ((uint32_t)(uint16_t)s) << 16;
  return __builtin_bit_cast(float, u);
}

__device__ inline f32x4 mfma16(short8v a, short8v b, f32x4 c) {
  return __builtin_amdgcn_mfma_f32_16x16x32_bf16(a, b, c, 0, 0, 0);
}

__device__ __forceinline__ void load8(const float* p, float* v) {
  float4 a = *(const float4*)p;
  float4 b = *(const float4*)(p + 4);
  v[0] = a.x; v[1] = a.y; v[2] = a.z; v[3] = a.w;
  v[4] = b.x; v[5] = b.y; v[6] = b.z; v[7] = b.w;
}

// ---------- u[l,rel,side][k] = sum_j W[l,rel,k,j] * a[l,rel,j] ----------
__global__ void compute_u_kernel(const float* __restrict__ Wsrc, const float* __restrict__ Wdst,
                                 const float* __restrict__ asrc, const float* __restrict__ adst,
                                 float* __restrict__ u) {
  int lr = blockIdx.x;
  int side = blockIdx.y;
  int k = threadIdx.x;
  const float* W = (side == 0 ? Wsrc : Wdst) + ((size_t)lr * D + k) * D;
  const float* a = (side == 0 ? asrc : adst) + (size_t)lr * D;
  float s = 0.f;
  for (int j = 0; j < D; ++j) s += W[j] * a[j];
  u[((size_t)lr * 2 + side) * D + k] = s;
}

// ---------- W split: Wh/Wl bf16, transposed [col][k] ----------
__global__ void wsplit_kernel(const float* __restrict__ Wsrc,
                              short* __restrict__ WhT, short* __restrict__ WlT) {
  int lr = blockIdx.x;
  const float* W = Wsrc + (size_t)lr * D * D;
  short* wh = WhT + (size_t)lr * D * D;
  short* wl = WlT + (size_t)lr * D * D;
  for (int i = threadIdx.x; i < D * D; i += blockDim.x) {
    int k = i >> 7, c = i & 127;
    float w = W[i];
    short h = f2bf(w);
    short l = f2bf(w - bf2f(h));
    wh[c * D + k] = h;
    wl[c * D + k] = l;
  }
}

// ---------- u split to augmented-W layout: [l][j][k], j=0..5 ----------
// j: 0=(rel0,src)->es0 1=(rel0,dst)->ed0 2=(rel1,src)->es1 3=(rel2,dst)->ed2
//    4=(rel2,src)->es2 5=(rel1,dst)->ed1
__global__ void usplit_kernel(const float* __restrict__ u,
                              short* __restrict__ uh, short* __restrict__ ul, int L) {
  int l = blockIdx.x;
  int j = blockIdx.y;
  int k = threadIdx.x;
  int rel, side;
  switch (j) {
    case 0: rel = 0; side = 0; break;
    case 1: rel = 0; side = 1; break;
    case 2: rel = 1; side = 0; break;
    case 3: rel = 2; side = 1; break;
    case 4: rel = 2; side = 0; break;
    default: rel = 1; side = 1; break;
  }
  float w = u[(((size_t)l * 3 + rel) * 2 + side) * D + k];
  short h = f2bf(w);
  uh[((size_t)l * 6 + j) * D + k] = h;
  ul[((size_t)l * 6 + j) * D + k] = f2bf(w - bf2f(h));
}

// ---------- CSR build ----------
__global__ void count_kernel(const int* __restrict__ dst, int* __restrict__ cnt, int E) {
  int i = blockIdx.x * blockDim.x + threadIdx.x;
  if (i < E) atomicAdd(&cnt[dst[i]], 1);
}

__global__ void count2_kernel(const int* __restrict__ csrc, const int* __restrict__ cdst,
                              int* __restrict__ cnt_bycon, int* __restrict__ cnt_byvar, int E) {
  int i = blockIdx.x * blockDim.x + threadIdx.x;
  if (i < E) {
    atomicAdd(&cnt_bycon[cdst[i]], 1);
    atomicAdd(&cnt_byvar[csrc[i]], 1);
  }
}

__global__ void bsum3_kernel(const int* __restrict__ c0, const int* __restrict__ c1,
                             const int* __restrict__ c2, int* __restrict__ bsums,
                             int n0, int n1, int n2, int pb0, int pb1, int pb2) {
  __shared__ int red[256];
  int y = blockIdx.y;
  const int* cnt = (y == 0) ? c0 : (y == 1) ? c1 : c2;
  int n  = (y == 0) ? n0 : (y == 1) ? n1 : n2;
  int pb = (y == 0) ? pb0 : (y == 1) ? pb1 : pb2;
  int b = blockIdx.x, t = threadIdx.x;
  int base = b * pb;
  if (base >= n) return;
  int end = base + pb; if (end > n) end = n;
  int s = 0;
  for (int i = base + t; i < end; i += 256) s += cnt[i];
  red[t] = s;
  __syncthreads();
  #pragma unroll
  for (int off = 128; off; off >>= 1) {
    if (t < off) red[t] += red[t + off];
    __syncthreads();
  }
  if (t == 0) bsums[y * 1024 + b] = red[0];
}

__global__ void bscan3_kernel(int* __restrict__ bsums,
                              int* __restrict__ t0, int* __restrict__ t1, int* __restrict__ t2) {
  __shared__ int sh[1024];
  int y = blockIdx.x, t = threadIdx.x;
  int* bs = bsums + y * 1024;
  int v = bs[t];
  sh[t] = v;
  __syncthreads();
  for (int off = 1; off < 1024; off <<= 1) {
    int u = (t >= off) ? sh[t - off] : 0;
    __syncthreads();
    sh[t] += u;
    __syncthreads();
  }
  bs[t] = sh[t] - v;
  if (t == 1023) {
    int* tot = (y == 0) ? t0 : (y == 1) ? t1 : t2;
    *tot = sh[1023];
  }
}

__global__ void scanfill3_kernel(const int* __restrict__ c0, const int* __restrict__ c1,
                                 const int* __restrict__ c2, const int* __restrict__ bsums,
                                 int* __restrict__ rp0, int* __restrict__ rp1, int* __restrict__ rp2,
                                 int* __restrict__ cu0, int* __restrict__ cu1, int* __restrict__ cu2,
                                 int n0, int n1, int n2, int pb0, int pb1, int pb2) {
  __shared__ int sh[256];
  int y = blockIdx.y;
  const int* cnt = (y == 0) ? c0 : (y == 1) ? c1 : c2;
  int* rowptr    = (y == 0) ? rp0 : (y == 1) ? rp1 : rp2;
  int* cursor    = (y == 0) ? cu0 : (y == 1) ? cu1 : cu2;
  int n  = (y == 0) ? n0 : (y == 1) ? n1 : n2;
  int pb = (y == 0) ? pb0 : (y == 1) ? pb1 : pb2;
  int b = blockIdx.x, t = threadIdx.x;
  int base = b * pb;
  if (base >= n) return;
  int end = base + pb; if (end > n) end = n;
  int run = bsums[y * 1024 + b];
  for (int tile = base; tile < end; tile += 256) {
    int i = tile + t;
    int c = (i < end) ? cnt[i] : 0;
    __syncthreads();
    sh[t] = c;
    __syncthreads();
    for (int off = 1; off < 256; off <<= 1) {
      int u = (t >= off) ? sh[t - off] : 0;
      __syncthreads();
      sh[t] += u;
      __syncthreads();
    }
    int excl = sh[t] - c;
    if (i < end) {
      rowptr[i] = run + excl;
      cursor[i] = run + excl;
    }
    run += sh[255];
  }
}

__global__ void fill_kernel(const int* __restrict__ dst, const int* __restrict__ src,
                            int* __restrict__ cursor, int* __restrict__ col, int E) {
  int i = blockIdx.x * blockDim.x + threadIdx.x;
  if (i < E) {
    int p = atomicAdd(&cursor[dst[i]], 1);
    col[p] = src[i];
  }
}

__global__ void fill2_kernel(const int* __restrict__ csrc, const int* __restrict__ cdst,
                             int* __restrict__ cur_bycon, int* __restrict__ cur_byvar,
                             int* __restrict__ col_bycon, int* __restrict__ col_byvar, int E) {
  int i = blockIdx.x * blockDim.x + threadIdx.x;
  if (i < E) {
    int s = csrc[i], d = cdst[i];
    int p = atomicAdd(&cur_bycon[d], 1);
    col_bycon[p] = s;
    int q = atomicAdd(&cur_byvar[s], 1);
    col_byvar[q] = d;
  }
}

// ---------- mm3r: barrier-free register-fragment matmul + augmented-u dots ----------
// One wave = 16 rows x 32 cols (colpair cp = wave-in-block). W frags in VGPR.
// X frags loaded global->VGPR in MFMA B-layout. cp==0 also computes the
// augmented u-tile (attention logits) via the same MFMA.
template<typename Tin>
__global__ __launch_bounds__(256) void mm3r_kernel(
    const Tin* __restrict__ Xv, const Tin* __restrict__ Xc,
    const short* __restrict__ wh0, const short* __restrict__ wl0,
    const short* __restrict__ wh1, const short* __restrict__ wl1,
    const short* __restrict__ wh2, const short* __restrict__ wl2,
    const short* __restrict__ uah, const short* __restrict__ ual,
    bf16* __restrict__ H0, bf16* __restrict__ H1, bf16* __restrict__ H2,
    float* __restrict__ es0, float* __restrict__ ed0,
    float* __restrict__ es1, float* __restrict__ ed2,
    float* __restrict__ es2, float* __restrict__ ed1,
    int V, int C, int b0, int b1, int b2) {
  int bid = blockIdx.x;
  const Tin* X; const short* wh; const short* wl; bf16* H;
  int nrows, lb, nblk, nu;
  const short* auh; const short* aul;
  float *o0, *o1, *o2, *o3;
  if (bid < b0) {
    X = Xv; wh = wh0; wl = wl0; H = H0; nrows = V; lb = bid; nblk = b0;
    nu = 4; auh = uah; aul = ual;
    o0 = es0; o1 = ed0; o2 = es1; o3 = ed2;
  } else if (bid < b1) {
    X = Xv; wh = wh1; wl = wl1; H = H1; nrows = V; lb = bid - b0; nblk = b1 - b0;
    nu = 0; auh = nullptr; aul = nullptr; o0 = o1 = o2 = o3 = nullptr;
  } else {
    X = Xc; wh = wh2; wl = wl2; H = H2; nrows = C; lb = bid - b1; nblk = b2 - b1;
    nu = 2; auh = uah + 4 * D; aul = ual + 4 * D;
    o0 = es2; o1 = ed1; o2 = o3 = nullptr;
  }
  int nchunks = (nrows + 15) >> 4;
  int tid = threadIdx.x;
  int cp = tid >> 6, lane = tid & 63;
  int c15 = lane & 15, q = lane >> 4;

  // one-time W fragment load (A-operand: row=lane&15 -> output col)
  short8v Wh_[2][4], Wl_[2][4];
  #pragma unroll
  for (int t = 0; t < 2; ++t) {
    #pragma unroll
    for (int ks = 0; ks < 4; ++ks) {
      int o = (cp * 32 + t * 16 + c15) * D + ks * 32 + q * 8;
      Wh_[t][ks] = *(const short8v*)&wh[o];
      Wl_[t][ks] = *(const short8v*)&wl[o];
    }
  }
  bool doaug = (cp == 0) && (nu > 0);
  short8v Uh_[4], Ul_[4];
  if (doaug) {
    #pragma unroll
    for (int ks = 0; ks < 4; ++ks) {
      if (c15 < nu) {
        int o = c15 * D + ks * 32 + q * 8;
        Uh_[ks] = *(const short8v*)&auh[o];
        Ul_[ks] = *(const short8v*)&aul[o];
      } else {
        Uh_[ks] = (short8v){0, 0, 0, 0, 0, 0, 0, 0};
        Ul_[ks] = (short8v){0, 0, 0, 0, 0, 0, 0, 0};
      }
    }
  }

  for (int ch = lb; ch < nchunks; ch += nblk) {
    int row = ch * 16 + c15;
    bool valid = row < nrows;
    if (!valid) row = nrows - 1;
    const Tin* xp = X + (size_t)row * D + q * 8;
    f32x4 a0 = (f32x4){0.f, 0.f, 0.f, 0.f};
    f32x4 a1 = (f32x4){0.f, 0.f, 0.f, 0.f};
    f32x4 a2 = (f32x4){0.f, 0.f, 0.f, 0.f};
    if constexpr (sizeof(Tin) == 2) {
      // bf16 input: X is exact high part, no split needed
      short8v xf[4];
      #pragma unroll
      for (int ks = 0; ks < 4; ++ks)
        xf[ks] = *(const short8v*)((const short*)xp + ks * 32);
      #pragma unroll
      for (int ks = 0; ks < 4; ++ks) {
        a0 = mfma16(Wh_[0][ks], xf[ks], a0);
        a0 = mfma16(Wl_[0][ks], xf[ks], a0);
        a1 = mfma16(Wh_[1][ks], xf[ks], a1);
        a1 = mfma16(Wl_[1][ks], xf[ks], a1);
        if (doaug) {
          a2 = mfma16(Uh_[ks], xf[ks], a2);
          a2 = mfma16(Ul_[ks], xf[ks], a2);
        }
      }
    } else {
      // fp32 input (layer 0): register split-bf16, 3-term MFMA
      short8v xh[4], xl[4];
      #pragma unroll
      for (int ks = 0; ks < 4; ++ks) {
        float v[8];
        load8((const float*)xp + ks * 32, v);
        #pragma unroll
        for (int j = 0; j < 8; ++j) {
          short hj = f2bf(v[j]);
          xh[ks][j] = hj;
          xl[ks][j] = f2bf(v[j] - bf2f(hj));
        }
      }
      #pragma unroll
      for (int ks = 0; ks < 4; ++ks) {
        a0 = mfma16(Wh_[0][ks], xh[ks], a0);
        a0 = mfma16(Wl_[0][ks], xh[ks], a0);
        a0 = mfma16(Wh_[0][ks], xl[ks], a0);
        a1 = mfma16(Wh_[1][ks], xh[ks], a1);
        a1 = mfma16(Wl_[1][ks], xh[ks], a1);
        a1 = mfma16(Wh_[1][ks], xl[ks], a1);
        if (doaug) {
          a2 = mfma16(Uh_[ks], xh[ks], a2);
          a2 = mfma16(Ul_[ks], xh[ks], a2);
          a2 = mfma16(Uh_[ks], xl[ks], a2);
        }
      }
    }
    if (valid) {
      short4 s0, s1;
      s0.x = f2bf(a0[0]); s0.y = f2bf(a0[1]); s0.z = f2bf(a0[2]); s0.w = f2bf(a0[3]);
      s1.x = f2bf(a1[0]); s1.y = f2bf(a1[1]); s1.z = f2bf(a1[2]); s1.w = f2bf(a1[3]);
      size_t hb = (size_t)row * D + cp * 32 + q * 4;
      *(short4*)((short*)H + hb) = s0;
      *(short4*)((short*)H + hb + 16) = s1;
      if (doaug && q == 0) {
        o0[row] = a2[0];
        o1[row] = a2[1];
        if (nu == 4) { o2[row] = a2[2]; o3[row] = a2[3]; }
      }
    }
  }
}

// ---------- alpha pass: per-dst softmax -> CSR-ordered (src, alpha) pairs ----------
__device__ __forceinline__ void alpha_rel(const int* __restrict__ rp, const int* __restrict__ col,
                                          const float* __restrict__ es, float edst,
                                          int gw, int lane, int2* __restrict__ edata) {
  int p0 = rp[gw];
  int deg = rp[gw + 1] - p0;
  if (deg <= 0) return;
  if (deg <= 64) {
    int s = 0; float e = -3.0e38f;
    if (lane < deg) {
      s = col[p0 + lane];
      float t = es[s] + edst;
      e = t > 0.f ? t : 0.2f * t;
    }
    float m = e;
    #pragma unroll
    for (int off = 32; off; off >>= 1) m = fmaxf(m, __shfl_xor(m, off));
    float ex = (lane < deg) ? __expf(e - m) : 0.f;
    float den = ex;
    #pragma unroll
    for (int off = 32; off; off >>= 1) den += __shfl_xor(den, off);
    float al = ex / (den + 1e-16f);
    if (lane < deg) {
      int2 v; v.x = s; v.y = __builtin_bit_cast(int, al);
      edata[p0 + lane] = v;
    }
  } else {
    float m = -3.0e38f;
    for (int j = lane; j < deg; j += 64) {
      int s = col[p0 + j];
      float t = es[s] + edst;
      t = t > 0.f ? t : 0.2f * t;
      m = fmaxf(m, t);
    }
    #pragma unroll
    for (int off = 32; off; off >>= 1) m = fmaxf(m, __shfl_xor(m, off));
    float den = 0.f;
    for (int j = lane; j < deg; j += 64) {
      int s = col[p0 + j];
      float t = es[s] + edst;
      t = t > 0.f ? t : 0.2f * t;
      den += __expf(t - m);
    }
    #pragma unroll
    for (int off = 32; off; off >>= 1) den += __shfl_xor(den, off);
    float inv = 1.f / (den + 1e-16f);
    for (int j = lane; j < deg; j += 64) {
      int s = col[p0 + j];
      float t = es[s] + edst;
      t = t > 0.f ? t : 0.2f * t;
      int2 v; v.x = s; v.y = __builtin_bit_cast(int, __expf(t - m) * inv);
      edata[p0 + j] = v;
    }
  }
}

__global__ void alpha_all_kernel(const int* __restrict__ rp0, const int* __restrict__ col0,
                                 const float* __restrict__ es0, const float* __restrict__ ed0,
                                 int2* __restrict__ eda0,
                                 const int* __restrict__ rp2, const int* __restrict__ col2,
                                 const float* __restrict__ es2, const float* __restrict__ ed2,
                                 int2* __restrict__ eda2,
                                 const int* __restrict__ rp1, const int* __restrict__ col1,
                                 const float* __restrict__ es1, const float* __restrict__ ed1,
                                 int2* __restrict__ eda1,
                                 int V, int C) {
  int gw = (int)(((size_t)blockIdx.x * blockDim.x + threadIdx.x) >> 6);
  int lane = threadIdx.x & 63;
  if (gw < V) {
    alpha_rel(rp0, col0, es0, ed0[gw], gw, lane, eda0);
    alpha_rel(rp2, col2, es2, ed2[gw], gw, lane, eda2);
  } else if (gw < V + C) {
    int g = gw - V;
    alpha_rel(rp1, col1, es1, ed1[g], g, lane, eda1);
  }
}

// ---------- gather pass ----------
__device__ __forceinline__ void agg_rel(const int2* __restrict__ edata, int p0, int p1,
                                        const bf16* __restrict__ hs, int l2,
                                        float& a0, float& a1) {
  int q = p0;
  while (q + 4 <= p1) {
    int2 e0 = edata[q], e1 = edata[q + 1], e2 = edata[q + 2], e3 = edata[q + 3];
    int s0 = __builtin_amdgcn_readfirstlane(e0.x);
    int s1 = __builtin_amdgcn_readfirstlane(e1.x);
    int s2 = __builtin_amdgcn_readfirstlane(e2.x);
    int s3 = __builtin_amdgcn_readfirstlane(e3.x);
    float w0 = __builtin_bit_cast(float, __builtin_amdgcn_readfirstlane(e0.y));
    float w1 = __builtin_bit_cast(float, __builtin_amdgcn_readfirstlane(e1.y));
    float w2 = __builtin_bit_cast(float, __builtin_amdgcn_readfirstlane(e2.y));
    float w3 = __builtin_bit_cast(float, __builtin_amdgcn_readfirstlane(e3.y));
    float2 h0 = ld2(&hs[(size_t)s0 * D + l2]);
    float2 h1 = ld2(&hs[(size_t)s1 * D + l2]);
    float2 h2 = ld2(&hs[(size_t)s2 * D + l2]);
    float2 h3 = ld2(&hs[(size_t)s3 * D + l2]);
    a0 += w0 * h0.x + w1 * h1.x + w2 * h2.x + w3 * h3.x;
    a1 += w0 * h0.y + w1 * h1.y + w2 * h2.y + w3 * h3.y;
    q += 4;
  }
  while (q < p1) {
    int2 e = edata[q++];
    int s = __builtin_amdgcn_readfirstlane(e.x);
    float w = __builtin_bit_cast(float, __builtin_amdgcn_readfirstlane(e.y));
    float2 h = ld2(&hs[(size_t)s * D + l2]);
    a0 += w * h.x;
    a1 += w * h.y;
  }
}

__global__ void agg_all_kernel(const int* __restrict__ rp0, const int2* __restrict__ eda0,
                               const bf16* __restrict__ hsv0, const float* __restrict__ b0,
                               const int* __restrict__ rp2, const int2* __restrict__ eda2,
                               const bf16* __restrict__ hsc, const float* __restrict__ b2,
                               const int* __restrict__ rp1, const int2* __restrict__ eda1,
                               const bf16* __restrict__ hsv1, const float* __restrict__ b1,
                               bf16* __restrict__ xv_out, bf16* __restrict__ xc_out, int V, int C) {
  int gw = (int)(((size_t)blockIdx.x * blockDim.x + threadIdx.x) >> 6);
  int lane = threadIdx.x & 63;
  int l2 = 2 * lane;
  if (gw < V) {
    float a0 = 0.f, a1 = 0.f;
    agg_rel(eda0, rp0[gw], rp0[gw + 1], hsv0, l2, a0, a1);
    agg_rel(eda2, rp2[gw], rp2[gw + 1], hsc, l2, a0, a1);
    float v0 = a0 + b0[l2] + b2[l2];
    float v1 = a1 + b0[l2 + 1] + b2[l2 + 1];
    st2(&xv_out[(size_t)gw * D + l2], v0 > 0.f ? v0 : 0.f, v1 > 0.f ? v1 : 0.f);
  } else if (gw < V + C) {
    int g = gw - V;
    float a0 = 0.f, a1 = 0.f;
    agg_rel(eda1, rp1[g], rp1[g + 1], hsv1, l2, a0, a1);
    float v0 = a0 + b1[l2];
    float v1 = a1 + b1[l2 + 1];
    st2(&xc_out[(size_t)g * D + l2], v0 > 0.f ? v0 : 0.f, v1 > 0.f ? v1 : 0.f);
  }
}

// ---------- pooling over sorted batch ids ----------
__global__ void pool_kernel(const bf16* __restrict__ xv, const int* __restrict__ batch,
                            float* __restrict__ pooled, float* __restrict__ cntf,
                            int rowsPerBlock, int V) {
  int j = threadIdx.x;
  int r0 = blockIdx.x * rowsPerBlock;
  if (r0 >= V) return;
  int rend = r0 + rowsPerBlock; if (rend > V) rend = V;
  int cur = batch[r0];
  float s = 0.f;
  int run = 0;
  for (int r = r0; r < rend; ++r) {
    int b = batch[r];
    if (b != cur) {
      atomicAdd(&pooled[(size_t)cur * D + j], s);
      if (j == 0) atomicAdd(&cntf[cur], (float)run);
      s = 0.f; run = 0; cur = b;
    }
    s += ld1(&xv[(size_t)r * D + j]);
    run++;
  }
  atomicAdd(&pooled[(size_t)cur * D + j], s);
  if (j == 0) atomicAdd(&cntf[cur], (float)run);
}

// ---------- final MLP ----------
__global__ void mlp_kernel(const float* __restrict__ pooled, const float* __restrict__ cntf,
                           const float* __restrict__ w1, const float* __restrict__ b1,
                           const float* __restrict__ w2, const float* __restrict__ b2,
                           float* __restrict__ out, int B) {
  __shared__ float P[32 * D];
  __shared__ float Hs[32 * D];
  int tid = threadIdx.x;
  if (B > 32) return;
  for (int i = tid; i < B * D; i += 256) {
    int r = i >> 7;
    P[i] = pooled[i] / fmaxf(cntf[r], 1.0f);
  }
  __syncthreads();
  for (int i = tid; i < B * D; i += 256) {
    int r = i >> 7, j = i & 127;
    float s = b1[j];
    for (int k = 0; k < D; ++k) s += P[r * D + k] * w1[k * D + j];
    Hs[i] = s > 0.f ? s : 0.f;
  }
  __syncthreads();
  if (tid < B) {
    float s = b2[0];
    for (int j = 0; j < D; ++j) s += Hs[tid * D + j] * w2[j];
    out[tid] = s;
  }
}

__global__ void zero_kernel(float* __restrict__ o, int n) {
  int i = blockIdx.x * blockDim.x + threadIdx.x;
  if (i < n) o[i] = 0.f;
}

// ---------- full pipeline (features stored bf16, compute fp32) ----------
static void run_all(const float* x_var, const float* x_con,
                    const float* W_src, const float* W_dst,
                    const float* att_src, const float* att_dst, const float* bias,
                    const float* mlp_w1, const float* mlp_b1,
                    const float* mlp_w2, const float* mlp_b2,
                    const int* e_neg_src, const int* e_neg_dst,
                    const int* e_con_src, const int* e_con_dst, const int* batch_var,
                    int V, int C, int L, int EN, int EC, int B,
                    char* ws, float* out, hipStream_t stream) {
  size_t off = 0;
  auto alloc = [&](size_t bytes) -> char* {
    char* p = ws + off;
    off = (off + bytes + 255) & ~(size_t)255;
    return p;
  };
  bf16* xv  = (bf16*)alloc((size_t)V * D * 2);
  bf16* xc  = (bf16*)alloc((size_t)C * D * 2);
  bf16* hsv0 = (bf16*)alloc((size_t)V * D * 2);
  bf16* hsv1 = (bf16*)alloc((size_t)V * D * 2);
  bf16* hsc  = (bf16*)alloc((size_t)C * D * 2);
  float* es0 = (float*)alloc((size_t)V * 4);
  float* ed0 = (float*)alloc((size_t)V * 4);
  float* es1 = (float*)alloc((size_t)V * 4);
  float* ed2 = (float*)alloc((size_t)V * 4);
  float* es2 = (float*)alloc((size_t)C * 4);
  float* ed1 = (float*)alloc((size_t)C * 4);
  float* u   = (float*)alloc((size_t)L * 3 * 2 * D * 4);
  short* whT = (short*)alloc((size_t)L * 3 * D * D * 2);
  short* wlT = (short*)alloc((size_t)L * 3 * D * D * 2);
  short* uh  = (short*)alloc((size_t)L * 6 * D * 2);
  short* ul  = (short*)alloc((size_t)L * 6 * D * 2);
  int* rp0  = (int*)alloc((size_t)(V + 1) * 4);
  int* rp1  = (int*)alloc((size_t)(C + 1) * 4);
  int* rp2  = (int*)alloc((size_t)(V + 1) * 4);
  int* curs = (int*)alloc((size_t)(2 * (size_t)V + C) * 4);
  int* cur0 = curs, *cur1 = curs + V, *cur2 = curs + V + C;
  int* col0 = (int*)alloc((size_t)EN * 4);
  int* col1 = (int*)alloc((size_t)EC * 4);
  int* col2 = (int*)alloc((size_t)EC * 4);
  int2* eda0 = (int2*)alloc((size_t)EN * 8);
  int2* eda1 = (int2*)alloc((size_t)EC * 8);
  int2* eda2 = (int2*)alloc((size_t)EC * 8);
  int* bsums = (int*)alloc((size_t)3 * 1024 * 4);
  float* pooled = (float*)alloc((size_t)(B * D + B) * 4);
  float* cntf = pooled + (size_t)B * D;

  hipMemsetAsync(curs, 0, (size_t)(2 * (size_t)V + C) * 4, stream);
  hipMemsetAsync(bsums, 0, (size_t)3 * 1024 * 4, stream);
  hipMemsetAsync(pooled, 0, (size_t)(B * D + B) * 4, stream);

  compute_u_kernel<<<dim3(L * 3, 2), D, 0, stream>>>(W_src, W_dst, att_src, att_dst, u);
  wsplit_kernel<<<L * 3, 256, 0, stream>>>(W_src, whT, wlT);
  usplit_kernel<<<dim3(L, 6), D, 0, stream>>>(u, uh, ul, L);

  const int tb = 256;
  count_kernel<<<(EN + tb - 1) / tb, tb, 0, stream>>>(e_neg_dst, cur0, EN);
  count2_kernel<<<(EC + tb - 1) / tb, tb, 0, stream>>>(e_con_src, e_con_dst, cur1, cur2, EC);

  auto pbof = [](int n) {
    int pb = ((n + 1023) / 1024 + 255) & ~255;
    return pb < 256 ? 256 : pb;
  };
  int pb0 = pbof(V), pb1 = pbof(C), pb2 = pbof(V);
  int nb0 = (V + pb0 - 1) / pb0, nb1 = (C + pb1 - 1) / pb1, nb2 = (V + pb2 - 1) / pb2;
  int nbmax = nb0 > nb1 ? nb0 : nb1; if (nb2 > nbmax) nbmax = nb2;
  bsum3_kernel<<<dim3(nbmax, 3), 256, 0, stream>>>(cur0, cur1, cur2, bsums, V, C, V, pb0, pb1, pb2);
  bscan3_kernel<<<3, 1024, 0, stream>>>(bsums, rp0 + V, rp1 + C, rp2 + V);
  scanfill3_kernel<<<dim3(nbmax, 3), 256, 0, stream>>>(cur0, cur1, cur2, bsums,
                                                       rp0, rp1, rp2, cur0, cur1, cur2,
                                                       V, C, V, pb0, pb1, pb2);

  fill_kernel<<<(EN + tb - 1) / tb, tb, 0, stream>>>(e_neg_dst, e_neg_src, cur0, col0, EN);
  fill2_kernel<<<(EC + tb - 1) / tb, tb, 0, stream>>>(e_con_src, e_con_dst, cur1, cur2, col1, col2, EC);

  auto Wh = [&](int l, int rel) { return whT + ((size_t)l * 3 + rel) * D * D; };
  auto Wl = [&](int l, int rel) { return wlT + ((size_t)l * 3 + rel) * D * D; };
  auto Bp = [&](int l, int rel) { return bias + ((size_t)l * 3 + rel) * D; };

  int gwaves = (V + C + 3) / 4;
  const int MB0 = 1024, MB1 = 2048, MB2 = 2560;

  for (int l = 0; l < L; ++l) {
    const short* uah = uh + (size_t)l * 6 * D;
    const short* ual = ul + (size_t)l * 6 * D;
    if (l == 0) {
      mm3r_kernel<float><<<MB2, 256, 0, stream>>>(
          x_var, x_con, Wh(l,0), Wl(l,0), Wh(l,1), Wl(l,1), Wh(l,2), Wl(l,2),
          uah, ual, hsv0, hsv1, hsc,
          es0, ed0, es1, ed2, es2, ed1, V, C, MB0, MB1, MB2);
    } else {
      mm3r_kernel<bf16><<<MB2, 256, 0, stream>>>(
          xv, xc, Wh(l,0), Wl(l,0), Wh(l,1), Wl(l,1), Wh(l,2), Wl(l,2),
          uah, ual, hsv0, hsv1, hsc,
          es0, ed0, es1, ed2, es2, ed1, V, C, MB0, MB1, MB2);
    }
    alpha_all_kernel<<<gwaves, 256, 0, stream>>>(
        rp0, col0, es0, ed0, eda0,
        rp2, col2, es2, ed2, eda2,
        rp1, col1, es1, ed1, eda1, V, C);
    agg_all_kernel<<<gwaves, 256, 0, stream>>>(
        rp0, eda0, hsv0, Bp(l,0),
        rp2, eda2, hsc,  Bp(l,2),
        rp1, eda1, hsv1, Bp(l,1),
        xv, xc, V, C);
  }

  pool_kernel<<<(V + 127) / 128, 128, 0, stream>>>(xv, batch_var, pooled, cntf, 128, V);
  mlp_kernel<<<1, 256, 0, stream>>>(pooled, cntf, mlp_w1, mlp_b1, mlp_w2, mlp_b2, out, B);
}

extern "C" void kernel_launch(void* const* d_in, const int* in_sizes, int n_in,
                              void* d_out, int out_size, void* d_ws, size_t ws_size,
                              hipStream_t stream) {
  const float* x_var   = (const float*)d_in[0];
  const float* x_con   = (const float*)d_in[1];
  const float* W_src   = (const float*)d_in[2];
  const float* W_dst   = (const float*)d_in[3];
  const float* att_src = (const float*)d_in[4];
  const float* att_dst = (const float*)d_in[5];
  const float* bias    = (const float*)d_in[6];
  const float* mlp_w1  = (const float*)d_in[7];
  const float* mlp_b1  = (const float*)d_in[8];
  const float* mlp_w2  = (const float*)d_in[9];
  const float* mlp_b2  = (const float*)d_in[10];
  const int* e_neg_src = (const int*)d_in[11];
  const int* e_neg_dst = (const int*)d_in[12];
  const int* e_con_src = (const int*)d_in[13];
  const int* e_con_dst = (const int*)d_in[14];
  const int* batch_var = (const int*)d_in[15];
  (void)n_in;

  const int V  = in_sizes[0] / D;
  const int C  = in_sizes[1] / D;
  const int L  = in_sizes[2] / (3 * D * D);
  const int EN = in_sizes[11];
  const int EC = in_sizes[13];
  const int B  = out_size;

  auto plan = [&]() -> size_t {
    size_t o = 0;
    auto add = [&](size_t b) { o = (o + b + 255) & ~(size_t)255; };
    add((size_t)V * D * 2); add((size_t)C * D * 2);
    add((size_t)V * D * 2); add((size_t)V * D * 2); add((size_t)C * D * 2);
    add((size_t)V * 4); add((size_t)V * 4); add((size_t)V * 4); add((size_t)V * 4);
    add((size_t)C * 4); add((size_t)C * 4);
    add((size_t)L * 3 * 2 * D * 4);
    add((size_t)L * 3 * D * D * 2); add((size_t)L * 3 * D * D * 2);
    add((size_t)L * 6 * D * 2); add((size_t)L * 6 * D * 2);
    add((size_t)(V + 1) * 4); add((size_t)(C + 1) * 4); add((size_t)(V + 1) * 4);
    add((size_t)(2 * (size_t)V + C) * 4);
    add((size_t)EN * 4); add((size_t)EC * 4); add((size_t)EC * 4);
    add((size_t)EN * 8); add((size_t)EC * 8); add((size_t)EC * 8);
    add((size_t)3 * 1024 * 4);
    add((size_t)(B * D + B) * 4);
    return o;
  };

  if (plan() <= ws_size) {
    run_all(x_var, x_con, W_src, W_dst, att_src, att_dst, bias,
            mlp_w1, mlp_b1, mlp_w2, mlp_b2,
            e_neg_src, e_neg_dst, e_con_src, e_con_dst, batch_var,
            V, C, L, EN, EC, B, (char*)d_ws, (float*)d_out, stream);
  } else {
    zero_kernel<<<(out_size + 63) / 64, 64, 0, stream>>>((float*)d_out, out_size);
  }
}

// Round 10
// 970.410 us; speedup vs baseline: 1.0046x; 1.0046x over previous
//
#include <hip/hip_runtime.h>
#include <hip/hip_bf16.h>
#include <cstdint>
#include <cstddef>

#define D 128

typedef __hip_bfloat16 bf16;
typedef __attribute__((ext_vector_type(8))) short short8v;   // 8 bf16 (4 VGPR)
typedef __attribute__((ext_vector_type(4))) float f32x4;     // MFMA 16x16 acc

// ---------- typed load/store helpers ----------
__device__ inline float ld1(const float* p) { return *p; }
__device__ inline float ld1(const bf16* p) { return __bfloat162float(*p); }
__device__ inline float2 ld2(const float* p) { return *(const float2*)p; }
__device__ inline float2 ld2(const bf16* p) {
  __hip_bfloat162 v = *(const __hip_bfloat162*)p;
  float2 r; r.x = __bfloat162float(v.x); r.y = __bfloat162float(v.y); return r;
}
__device__ inline void st2(float* p, float a, float b) {
  float2 v; v.x = a; v.y = b; *(float2*)p = v;
}
__device__ inline void st2(bf16* p, float a, float b) {
  __hip_bfloat162 v; v.x = __float2bfloat16(a); v.y = __float2bfloat16(b);
  *(__hip_bfloat162*)p = v;
}

// bf16 helpers via intrinsic casts (compiler fuses pairs into v_cvt_pk_bf16_f32)
__device__ inline short f2bf(float x) {
  bf16 h = __float2bfloat16(x);
  return *(short*)&h;
}
__device__ inline float bf2f(short s) {
  uint32_t u = ((uint32_t)(uint16_t)s) << 16;
  return __builtin_bit_cast(float, u);
}

__device__ inline f32x4 mfma16(short8v a, short8v b, f32x4 c) {
  return __builtin_amdgcn_mfma_f32_16x16x32_bf16(a, b, c, 0, 0, 0);
}

__device__ __forceinline__ void load8(const float* p, float* v) {
  float4 a = *(const float4*)p;
  float4 b = *(const float4*)(p + 4);
  v[0] = a.x; v[1] = a.y; v[2] = a.z; v[3] = a.w;
  v[4] = b.x; v[5] = b.y; v[6] = b.z; v[7] = b.w;
}

// ---------- u[l,rel,side][k] = sum_j W[l,rel,k,j] * a[l,rel,j] ----------
__global__ void compute_u_kernel(const float* __restrict__ Wsrc, const float* __restrict__ Wdst,
                                 const float* __restrict__ asrc, const float* __restrict__ adst,
                                 float* __restrict__ u) {
  int lr = blockIdx.x;
  int side = blockIdx.y;
  int k = threadIdx.x;
  const float* W = (side == 0 ? Wsrc : Wdst) + ((size_t)lr * D + k) * D;
  const float* a = (side == 0 ? asrc : adst) + (size_t)lr * D;
  float s = 0.f;
  for (int j = 0; j < D; ++j) s += W[j] * a[j];
  u[((size_t)lr * 2 + side) * D + k] = s;
}

// ---------- W split: Wh/Wl bf16, transposed [col][k] ----------
__global__ void wsplit_kernel(const float* __restrict__ Wsrc,
                              short* __restrict__ WhT, short* __restrict__ WlT) {
  int lr = blockIdx.x;
  const float* W = Wsrc + (size_t)lr * D * D;
  short* wh = WhT + (size_t)lr * D * D;
  short* wl = WlT + (size_t)lr * D * D;
  for (int i = threadIdx.x; i < D * D; i += blockDim.x) {
    int k = i >> 7, c = i & 127;
    float w = W[i];
    short h = f2bf(w);
    short l = f2bf(w - bf2f(h));
    wh[c * D + k] = h;
    wl[c * D + k] = l;
  }
}

// ---------- u split to augmented-W layout: [l][j][k], j=0..5 ----------
__global__ void usplit_kernel(const float* __restrict__ u,
                              short* __restrict__ uh, short* __restrict__ ul, int L) {
  int l = blockIdx.x;
  int j = blockIdx.y;
  int k = threadIdx.x;
  int rel, side;
  switch (j) {
    case 0: rel = 0; side = 0; break;
    case 1: rel = 0; side = 1; break;
    case 2: rel = 1; side = 0; break;
    case 3: rel = 2; side = 1; break;
    case 4: rel = 2; side = 0; break;
    default: rel = 1; side = 1; break;
  }
  float w = u[(((size_t)l * 3 + rel) * 2 + side) * D + k];
  short h = f2bf(w);
  uh[((size_t)l * 6 + j) * D + k] = h;
  ul[((size_t)l * 6 + j) * D + k] = f2bf(w - bf2f(h));
}

// ---------- CSR build ----------
__global__ void count_kernel(const int* __restrict__ dst, int* __restrict__ cnt, int E) {
  int i = blockIdx.x * blockDim.x + threadIdx.x;
  if (i < E) atomicAdd(&cnt[dst[i]], 1);
}

__global__ void count2_kernel(const int* __restrict__ csrc, const int* __restrict__ cdst,
                              int* __restrict__ cnt_bycon, int* __restrict__ cnt_byvar, int E) {
  int i = blockIdx.x * blockDim.x + threadIdx.x;
  if (i < E) {
    atomicAdd(&cnt_bycon[cdst[i]], 1);
    atomicAdd(&cnt_byvar[csrc[i]], 1);
  }
}

__global__ void bsum3_kernel(const int* __restrict__ c0, const int* __restrict__ c1,
                             const int* __restrict__ c2, int* __restrict__ bsums,
                             int n0, int n1, int n2, int pb0, int pb1, int pb2) {
  __shared__ int red[256];
  int y = blockIdx.y;
  const int* cnt = (y == 0) ? c0 : (y == 1) ? c1 : c2;
  int n  = (y == 0) ? n0 : (y == 1) ? n1 : n2;
  int pb = (y == 0) ? pb0 : (y == 1) ? pb1 : pb2;
  int b = blockIdx.x, t = threadIdx.x;
  int base = b * pb;
  if (base >= n) return;
  int end = base + pb; if (end > n) end = n;
  int s = 0;
  for (int i = base + t; i < end; i += 256) s += cnt[i];
  red[t] = s;
  __syncthreads();
  #pragma unroll
  for (int off = 128; off; off >>= 1) {
    if (t < off) red[t] += red[t + off];
    __syncthreads();
  }
  if (t == 0) bsums[y * 1024 + b] = red[0];
}

__global__ void bscan3_kernel(int* __restrict__ bsums,
                              int* __restrict__ t0, int* __restrict__ t1, int* __restrict__ t2) {
  __shared__ int sh[1024];
  int y = blockIdx.x, t = threadIdx.x;
  int* bs = bsums + y * 1024;
  int v = bs[t];
  sh[t] = v;
  __syncthreads();
  for (int off = 1; off < 1024; off <<= 1) {
    int u = (t >= off) ? sh[t - off] : 0;
    __syncthreads();
    sh[t] += u;
    __syncthreads();
  }
  bs[t] = sh[t] - v;
  if (t == 1023) {
    int* tot = (y == 0) ? t0 : (y == 1) ? t1 : t2;
    *tot = sh[1023];
  }
}

__global__ void scanfill3_kernel(const int* __restrict__ c0, const int* __restrict__ c1,
                                 const int* __restrict__ c2, const int* __restrict__ bsums,
                                 int* __restrict__ rp0, int* __restrict__ rp1, int* __restrict__ rp2,
                                 int* __restrict__ cu0, int* __restrict__ cu1, int* __restrict__ cu2,
                                 int n0, int n1, int n2, int pb0, int pb1, int pb2) {
  __shared__ int sh[256];
  int y = blockIdx.y;
  const int* cnt = (y == 0) ? c0 : (y == 1) ? c1 : c2;
  int* rowptr    = (y == 0) ? rp0 : (y == 1) ? rp1 : rp2;
  int* cursor    = (y == 0) ? cu0 : (y == 1) ? cu1 : cu2;
  int n  = (y == 0) ? n0 : (y == 1) ? n1 : n2;
  int pb = (y == 0) ? pb0 : (y == 1) ? pb1 : pb2;
  int b = blockIdx.x, t = threadIdx.x;
  int base = b * pb;
  if (base >= n) return;
  int end = base + pb; if (end > n) end = n;
  int run = bsums[y * 1024 + b];
  for (int tile = base; tile < end; tile += 256) {
    int i = tile + t;
    int c = (i < end) ? cnt[i] : 0;
    __syncthreads();
    sh[t] = c;
    __syncthreads();
    for (int off = 1; off < 256; off <<= 1) {
      int u = (t >= off) ? sh[t - off] : 0;
      __syncthreads();
      sh[t] += u;
      __syncthreads();
    }
    int excl = sh[t] - c;
    if (i < end) {
      rowptr[i] = run + excl;
      cursor[i] = run + excl;
    }
    run += sh[255];
  }
}

__global__ void fill_kernel(const int* __restrict__ dst, const int* __restrict__ src,
                            int* __restrict__ cursor, int* __restrict__ col, int E) {
  int i = blockIdx.x * blockDim.x + threadIdx.x;
  if (i < E) {
    int p = atomicAdd(&cursor[dst[i]], 1);
    col[p] = src[i];
  }
}

__global__ void fill2_kernel(const int* __restrict__ csrc, const int* __restrict__ cdst,
                             int* __restrict__ cur_bycon, int* __restrict__ cur_byvar,
                             int* __restrict__ col_bycon, int* __restrict__ col_byvar, int E) {
  int i = blockIdx.x * blockDim.x + threadIdx.x;
  if (i < E) {
    int s = csrc[i], d = cdst[i];
    int p = atomicAdd(&cur_bycon[d], 1);
    col_bycon[p] = s;
    int q = atomicAdd(&cur_byvar[s], 1);
    col_byvar[q] = d;
  }
}

// ---------- mm3r v2: barrier-free register-fragment matmul, prefetched ----------
template<typename Tin>
__global__ __launch_bounds__(256) void mm3r_kernel(
    const Tin* __restrict__ Xv, const Tin* __restrict__ Xc,
    const short* __restrict__ wh0, const short* __restrict__ wl0,
    const short* __restrict__ wh1, const short* __restrict__ wl1,
    const short* __restrict__ wh2, const short* __restrict__ wl2,
    const short* __restrict__ uah, const short* __restrict__ ual,
    bf16* __restrict__ H0, bf16* __restrict__ H1, bf16* __restrict__ H2,
    float* __restrict__ es0, float* __restrict__ ed0,
    float* __restrict__ es1, float* __restrict__ ed2,
    float* __restrict__ es2, float* __restrict__ ed1,
    int V, int C, int b0, int b1, int b2) {
  int bid = blockIdx.x;
  const Tin* X; const short* wh; const short* wl; bf16* H;
  int nrows, lb, nblk, nu;
  const short* auh; const short* aul;
  float *o0, *o1, *o2, *o3;
  if (bid < b0) {
    X = Xv; wh = wh0; wl = wl0; H = H0; nrows = V; lb = bid; nblk = b0;
    nu = 4; auh = uah; aul = ual;
    o0 = es0; o1 = ed0; o2 = es1; o3 = ed2;
  } else if (bid < b1) {
    X = Xv; wh = wh1; wl = wl1; H = H1; nrows = V; lb = bid - b0; nblk = b1 - b0;
    nu = 0; auh = nullptr; aul = nullptr; o0 = o1 = o2 = o3 = nullptr;
  } else {
    X = Xc; wh = wh2; wl = wl2; H = H2; nrows = C; lb = bid - b1; nblk = b2 - b1;
    nu = 2; auh = uah + 4 * D; aul = ual + 4 * D;
    o0 = es2; o1 = ed1; o2 = o3 = nullptr;
  }
  int nchunks = (nrows + 15) >> 4;
  if (lb >= nchunks) return;
  int tid = threadIdx.x;
  int cp = tid >> 6, lane = tid & 63;
  int c15 = lane & 15, q = lane >> 4;

  // one-time W fragment load (A-operand: row=lane&15 -> output col)
  short8v Wh_[2][4], Wl_[2][4];
  #pragma unroll
  for (int t = 0; t < 2; ++t) {
    #pragma unroll
    for (int ks = 0; ks < 4; ++ks) {
      int o = (cp * 32 + t * 16 + c15) * D + ks * 32 + q * 8;
      Wh_[t][ks] = *(const short8v*)&wh[o];
      Wl_[t][ks] = *(const short8v*)&wl[o];
    }
  }
  bool doaug = (cp == 0) && (nu > 0);
  short8v Uh_[4], Ul_[4];
  if (doaug) {
    #pragma unroll
    for (int ks = 0; ks < 4; ++ks) {
      if (c15 < nu) {
        int o = c15 * D + ks * 32 + q * 8;
        Uh_[ks] = *(const short8v*)&auh[o];
        Ul_[ks] = *(const short8v*)&aul[o];
      } else {
        Uh_[ks] = (short8v){0, 0, 0, 0, 0, 0, 0, 0};
        Ul_[ks] = (short8v){0, 0, 0, 0, 0, 0, 0, 0};
      }
    }
  }

  if constexpr (sizeof(Tin) == 2) {
    // bf16 path: X is exact high part; software prefetch next chunk
    auto xaddr = [&](int ch) -> const short* {
      int row = ch * 16 + c15;
      if (row >= nrows) row = nrows - 1;
      return (const short*)X + (size_t)row * D + q * 8;
    };
    short8v xf[4];
    {
      const short* xp = xaddr(lb);
      #pragma unroll
      for (int ks = 0; ks < 4; ++ks) xf[ks] = *(const short8v*)(xp + ks * 32);
    }
    for (int ch = lb; ch < nchunks; ch += nblk) {
      int nch = ch + nblk;
      short8v xn[4];
      if (nch < nchunks) {
        const short* xp = xaddr(nch);
        #pragma unroll
        for (int ks = 0; ks < 4; ++ks) xn[ks] = *(const short8v*)(xp + ks * 32);
      }
      f32x4 a0 = (f32x4){0.f, 0.f, 0.f, 0.f};
      f32x4 a1 = (f32x4){0.f, 0.f, 0.f, 0.f};
      f32x4 a2 = (f32x4){0.f, 0.f, 0.f, 0.f};
      #pragma unroll
      for (int ks = 0; ks < 4; ++ks) {
        a0 = mfma16(Wh_[0][ks], xf[ks], a0);
        a0 = mfma16(Wl_[0][ks], xf[ks], a0);
        a1 = mfma16(Wh_[1][ks], xf[ks], a1);
        a1 = mfma16(Wl_[1][ks], xf[ks], a1);
        if (doaug) {
          a2 = mfma16(Uh_[ks], xf[ks], a2);
          a2 = mfma16(Ul_[ks], xf[ks], a2);
        }
      }
      int row = ch * 16 + c15;
      if (row < nrows) {
        short4 s0, s1;
        s0.x = f2bf(a0[0]); s0.y = f2bf(a0[1]); s0.z = f2bf(a0[2]); s0.w = f2bf(a0[3]);
        s1.x = f2bf(a1[0]); s1.y = f2bf(a1[1]); s1.z = f2bf(a1[2]); s1.w = f2bf(a1[3]);
        size_t hb = (size_t)row * D + cp * 32 + q * 4;
        *(short4*)((short*)H + hb) = s0;
        *(short4*)((short*)H + hb + 16) = s1;
        if (doaug && q == 0) {
          o0[row] = a2[0];
          o1[row] = a2[1];
          if (nu == 4) { o2[row] = a2[2]; o3[row] = a2[3]; }
        }
      }
      #pragma unroll
      for (int ks = 0; ks < 4; ++ks) xf[ks] = xn[ks];
    }
  } else {
    // fp32 path (layer 0): register split-bf16, 3-term MFMA
    for (int ch = lb; ch < nchunks; ch += nblk) {
      int row = ch * 16 + c15;
      bool valid = row < nrows;
      if (!valid) row = nrows - 1;
      const Tin* xp = X + (size_t)row * D + q * 8;
      f32x4 a0 = (f32x4){0.f, 0.f, 0.f, 0.f};
      f32x4 a1 = (f32x4){0.f, 0.f, 0.f, 0.f};
      f32x4 a2 = (f32x4){0.f, 0.f, 0.f, 0.f};
      short8v xh[4], xl[4];
      #pragma unroll
      for (int ks = 0; ks < 4; ++ks) {
        float v[8];
        load8((const float*)xp + ks * 32, v);
        #pragma unroll
        for (int j = 0; j < 8; ++j) {
          short hj = f2bf(v[j]);
          xh[ks][j] = hj;
          xl[ks][j] = f2bf(v[j] - bf2f(hj));
        }
      }
      #pragma unroll
      for (int ks = 0; ks < 4; ++ks) {
        a0 = mfma16(Wh_[0][ks], xh[ks], a0);
        a0 = mfma16(Wl_[0][ks], xh[ks], a0);
        a0 = mfma16(Wh_[0][ks], xl[ks], a0);
        a1 = mfma16(Wh_[1][ks], xh[ks], a1);
        a1 = mfma16(Wl_[1][ks], xh[ks], a1);
        a1 = mfma16(Wh_[1][ks], xl[ks], a1);
        if (doaug) {
          a2 = mfma16(Uh_[ks], xh[ks], a2);
          a2 = mfma16(Ul_[ks], xh[ks], a2);
          a2 = mfma16(Uh_[ks], xl[ks], a2);
        }
      }
      if (valid) {
        short4 s0, s1;
        s0.x = f2bf(a0[0]); s0.y = f2bf(a0[1]); s0.z = f2bf(a0[2]); s0.w = f2bf(a0[3]);
        s1.x = f2bf(a1[0]); s1.y = f2bf(a1[1]); s1.z = f2bf(a1[2]); s1.w = f2bf(a1[3]);
        size_t hb = (size_t)row * D + cp * 32 + q * 4;
        *(short4*)((short*)H + hb) = s0;
        *(short4*)((short*)H + hb + 16) = s1;
        if (doaug && q == 0) {
          o0[row] = a2[0];
          o1[row] = a2[1];
          if (nu == 4) { o2[row] = a2[2]; o3[row] = a2[3]; }
        }
      }
    }
  }
}

// ---------- alpha pass: per-dst softmax -> CSR-ordered (src, alpha) pairs ----------
__device__ __forceinline__ void alpha_rel(const int* __restrict__ rp, const int* __restrict__ col,
                                          const float* __restrict__ es, float edst,
                                          int gw, int lane, int2* __restrict__ edata) {
  int p0 = rp[gw];
  int deg = rp[gw + 1] - p0;
  if (deg <= 0) return;
  if (deg <= 64) {
    int s = 0; float e = -3.0e38f;
    if (lane < deg) {
      s = col[p0 + lane];
      float t = es[s] + edst;
      e = t > 0.f ? t : 0.2f * t;
    }
    float m = e;
    #pragma unroll
    for (int off = 32; off; off >>= 1) m = fmaxf(m, __shfl_xor(m, off));
    float ex = (lane < deg) ? __expf(e - m) : 0.f;
    float den = ex;
    #pragma unroll
    for (int off = 32; off; off >>= 1) den += __shfl_xor(den, off);
    float al = ex / (den + 1e-16f);
    if (lane < deg) {
      int2 v; v.x = s; v.y = __builtin_bit_cast(int, al);
      edata[p0 + lane] = v;
    }
  } else {
    float m = -3.0e38f;
    for (int j = lane; j < deg; j += 64) {
      int s = col[p0 + j];
      float t = es[s] + edst;
      t = t > 0.f ? t : 0.2f * t;
      m = fmaxf(m, t);
    }
    #pragma unroll
    for (int off = 32; off; off >>= 1) m = fmaxf(m, __shfl_xor(m, off));
    float den = 0.f;
    for (int j = lane; j < deg; j += 64) {
      int s = col[p0 + j];
      float t = es[s] + edst;
      t = t > 0.f ? t : 0.2f * t;
      den += __expf(t - m);
    }
    #pragma unroll
    for (int off = 32; off; off >>= 1) den += __shfl_xor(den, off);
    float inv = 1.f / (den + 1e-16f);
    for (int j = lane; j < deg; j += 64) {
      int s = col[p0 + j];
      float t = es[s] + edst;
      t = t > 0.f ? t : 0.2f * t;
      int2 v; v.x = s; v.y = __builtin_bit_cast(int, __expf(t - m) * inv);
      edata[p0 + j] = v;
    }
  }
}

__global__ void alpha_all_kernel(const int* __restrict__ rp0, const int* __restrict__ col0,
                                 const float* __restrict__ es0, const float* __restrict__ ed0,
                                 int2* __restrict__ eda0,
                                 const int* __restrict__ rp2, const int* __restrict__ col2,
                                 const float* __restrict__ es2, const float* __restrict__ ed2,
                                 int2* __restrict__ eda2,
                                 const int* __restrict__ rp1, const int* __restrict__ col1,
                                 const float* __restrict__ es1, const float* __restrict__ ed1,
                                 int2* __restrict__ eda1,
                                 int V, int C) {
  int gw = (int)(((size_t)blockIdx.x * blockDim.x + threadIdx.x) >> 6);
  int lane = threadIdx.x & 63;
  if (gw < V) {
    alpha_rel(rp0, col0, es0, ed0[gw], gw, lane, eda0);
    alpha_rel(rp2, col2, es2, ed2[gw], gw, lane, eda2);
  } else if (gw < V + C) {
    int g = gw - V;
    alpha_rel(rp1, col1, es1, ed1[g], g, lane, eda1);
  }
}

// ---------- gather pass: half-wave scheme, 2 edges per wave, 8 B/lane ----------
__device__ __forceinline__ void gload4(const bf16* p, float* h) {
  short4 s = *(const short4*)p;
  h[0] = bf2f(s.x); h[1] = bf2f(s.y); h[2] = bf2f(s.z); h[3] = bf2f(s.w);
}

__device__ __forceinline__ void agg_rel2(const int2* __restrict__ edata, int p0, int p1,
                                         const bf16* __restrict__ hs, int c4, int half,
                                         float* a) {
  int q = p0 + half;
  while (q + 6 < p1) {                       // 4 edges per half (8 total) in flight
    int2 e0 = edata[q], e1 = edata[q + 2], e2 = edata[q + 4], e3 = edata[q + 6];
    float h0[4], h1[4], h2[4], h3[4];
    gload4(&hs[(size_t)e0.x * D + c4], h0);
    gload4(&hs[(size_t)e1.x * D + c4], h1);
    gload4(&hs[(size_t)e2.x * D + c4], h2);
    gload4(&hs[(size_t)e3.x * D + c4], h3);
    float w0 = __builtin_bit_cast(float, e0.y);
    float w1 = __builtin_bit_cast(float, e1.y);
    float w2 = __builtin_bit_cast(float, e2.y);
    float w3 = __builtin_bit_cast(float, e3.y);
    #pragma unroll
    for (int j = 0; j < 4; ++j)
      a[j] += w0 * h0[j] + w1 * h1[j] + w2 * h2[j] + w3 * h3[j];
    q += 8;
  }
  while (q < p1) {
    int2 e = edata[q];
    float h[4];
    gload4(&hs[(size_t)e.x * D + c4], h);
    float w = __builtin_bit_cast(float, e.y);
    #pragma unroll
    for (int j = 0; j < 4; ++j) a[j] += w * h[j];
    q += 2;
  }
}

__global__ void agg_all_kernel(const int* __restrict__ rp0, const int2* __restrict__ eda0,
                               const bf16* __restrict__ hsv0, const float* __restrict__ b0,
                               const int* __restrict__ rp2, const int2* __restrict__ eda2,
                               const bf16* __restrict__ hsc, const float* __restrict__ b2,
                               const int* __restrict__ rp1, const int2* __restrict__ eda1,
                               const bf16* __restrict__ hsv1, const float* __restrict__ b1,
                               bf16* __restrict__ xv_out, bf16* __restrict__ xc_out, int V, int C) {
  int gw = (int)(((size_t)blockIdx.x * blockDim.x + threadIdx.x) >> 6);
  int lane = threadIdx.x & 63;
  int half = lane >> 5;
  int c4 = (lane & 31) * 4;
  float a[4] = {0.f, 0.f, 0.f, 0.f};
  if (gw < V) {
    agg_rel2(eda0, rp0[gw], rp0[gw + 1], hsv0, c4, half, a);
    agg_rel2(eda2, rp2[gw], rp2[gw + 1], hsc, c4, half, a);
    #pragma unroll
    for (int j = 0; j < 4; ++j) a[j] += __shfl_xor(a[j], 32);
    if (half == 0) {
      float4 ba = *(const float4*)&b0[c4];
      float4 bb = *(const float4*)&b2[c4];
      float v0 = a[0] + ba.x + bb.x, v1 = a[1] + ba.y + bb.y;
      float v2 = a[2] + ba.z + bb.z, v3 = a[3] + ba.w + bb.w;
      short4 o;
      o.x = f2bf(v0 > 0.f ? v0 : 0.f);
      o.y = f2bf(v1 > 0.f ? v1 : 0.f);
      o.z = f2bf(v2 > 0.f ? v2 : 0.f);
      o.w = f2bf(v3 > 0.f ? v3 : 0.f);
      *(short4*)((short*)xv_out + (size_t)gw * D + c4) = o;
    }
  } else if (gw < V + C) {
    int g = gw - V;
    agg_rel2(eda1, rp1[g], rp1[g + 1], hsv1, c4, half, a);
    #pragma unroll
    for (int j = 0; j < 4; ++j) a[j] += __shfl_xor(a[j], 32);
    if (half == 0) {
      float4 ba = *(const float4*)&b1[c4];
      float v0 = a[0] + ba.x, v1 = a[1] + ba.y;
      float v2 = a[2] + ba.z, v3 = a[3] + ba.w;
      short4 o;
      o.x = f2bf(v0 > 0.f ? v0 : 0.f);
      o.y = f2bf(v1 > 0.f ? v1 : 0.f);
      o.z = f2bf(v2 > 0.f ? v2 : 0.f);
      o.w = f2bf(v3 > 0.f ? v3 : 0.f);
      *(short4*)((short*)xc_out + (size_t)g * D + c4) = o;
    }
  }
}

// ---------- pooling over sorted batch ids ----------
__global__ void pool_kernel(const bf16* __restrict__ xv, const int* __restrict__ batch,
                            float* __restrict__ pooled, float* __restrict__ cntf,
                            int rowsPerBlock, int V) {
  int j = threadIdx.x;
  int r0 = blockIdx.x * rowsPerBlock;
  if (r0 >= V) return;
  int rend = r0 + rowsPerBlock; if (rend > V) rend = V;
  int cur = batch[r0];
  float s = 0.f;
  int run = 0;
  for (int r = r0; r < rend; ++r) {
    int b = batch[r];
    if (b != cur) {
      atomicAdd(&pooled[(size_t)cur * D + j], s);
      if (j == 0) atomicAdd(&cntf[cur], (float)run);
      s = 0.f; run = 0; cur = b;
    }
    s += ld1(&xv[(size_t)r * D + j]);
    run++;
  }
  atomicAdd(&pooled[(size_t)cur * D + j], s);
  if (j == 0) atomicAdd(&cntf[cur], (float)run);
}

// ---------- final MLP ----------
__global__ void mlp_kernel(const float* __restrict__ pooled, const float* __restrict__ cntf,
                           const float* __restrict__ w1, const float* __restrict__ b1,
                           const float* __restrict__ w2, const float* __restrict__ b2,
                           float* __restrict__ out, int B) {
  __shared__ float P[32 * D];
  __shared__ float Hs[32 * D];
  int tid = threadIdx.x;
  if (B > 32) return;
  for (int i = tid; i < B * D; i += 256) {
    int r = i >> 7;
    P[i] = pooled[i] / fmaxf(cntf[r], 1.0f);
  }
  __syncthreads();
  for (int i = tid; i < B * D; i += 256) {
    int r = i >> 7, j = i & 127;
    float s = b1[j];
    for (int k = 0; k < D; ++k) s += P[r * D + k] * w1[k * D + j];
    Hs[i] = s > 0.f ? s : 0.f;
  }
  __syncthreads();
  if (tid < B) {
    float s = b2[0];
    for (int j = 0; j < D; ++j) s += Hs[tid * D + j] * w2[j];
    out[tid] = s;
  }
}

__global__ void zero_kernel(float* __restrict__ o, int n) {
  int i = blockIdx.x * blockDim.x + threadIdx.x;
  if (i < n) o[i] = 0.f;
}

// ---------- full pipeline (features stored bf16, compute fp32) ----------
static void run_all(const float* x_var, const float* x_con,
                    const float* W_src, const float* W_dst,
                    const float* att_src, const float* att_dst, const float* bias,
                    const float* mlp_w1, const float* mlp_b1,
                    const float* mlp_w2, const float* mlp_b2,
                    const int* e_neg_src, const int* e_neg_dst,
                    const int* e_con_src, const int* e_con_dst, const int* batch_var,
                    int V, int C, int L, int EN, int EC, int B,
                    char* ws, float* out, hipStream_t stream) {
  size_t off = 0;
  auto alloc = [&](size_t bytes) -> char* {
    char* p = ws + off;
    off = (off + bytes + 255) & ~(size_t)255;
    return p;
  };
  bf16* xv  = (bf16*)alloc((size_t)V * D * 2);
  bf16* xc  = (bf16*)alloc((size_t)C * D * 2);
  bf16* hsv0 = (bf16*)alloc((size_t)V * D * 2);
  bf16* hsv1 = (bf16*)alloc((size_t)V * D * 2);
  bf16* hsc  = (bf16*)alloc((size_t)C * D * 2);
  float* es0 = (float*)alloc((size_t)V * 4);
  float* ed0 = (float*)alloc((size_t)V * 4);
  float* es1 = (float*)alloc((size_t)V * 4);
  float* ed2 = (float*)alloc((size_t)V * 4);
  float* es2 = (float*)alloc((size_t)C * 4);
  float* ed1 = (float*)alloc((size_t)C * 4);
  float* u   = (float*)alloc((size_t)L * 3 * 2 * D * 4);
  short* whT = (short*)alloc((size_t)L * 3 * D * D * 2);
  short* wlT = (short*)alloc((size_t)L * 3 * D * D * 2);
  short* uh  = (short*)alloc((size_t)L * 6 * D * 2);
  short* ul  = (short*)alloc((size_t)L * 6 * D * 2);
  int* rp0  = (int*)alloc((size_t)(V + 1) * 4);
  int* rp1  = (int*)alloc((size_t)(C + 1) * 4);
  int* rp2  = (int*)alloc((size_t)(V + 1) * 4);
  int* curs = (int*)alloc((size_t)(2 * (size_t)V + C) * 4);
  int* cur0 = curs, *cur1 = curs + V, *cur2 = curs + V + C;
  int* col0 = (int*)alloc((size_t)EN * 4);
  int* col1 = (int*)alloc((size_t)EC * 4);
  int* col2 = (int*)alloc((size_t)EC * 4);
  int2* eda0 = (int2*)alloc((size_t)EN * 8);
  int2* eda1 = (int2*)alloc((size_t)EC * 8);
  int2* eda2 = (int2*)alloc((size_t)EC * 8);
  int* bsums = (int*)alloc((size_t)3 * 1024 * 4);
  float* pooled = (float*)alloc((size_t)(B * D + B) * 4);
  float* cntf = pooled + (size_t)B * D;

  hipMemsetAsync(curs, 0, (size_t)(2 * (size_t)V + C) * 4, stream);
  hipMemsetAsync(bsums, 0, (size_t)3 * 1024 * 4, stream);
  hipMemsetAsync(pooled, 0, (size_t)(B * D + B) * 4, stream);

  compute_u_kernel<<<dim3(L * 3, 2), D, 0, stream>>>(W_src, W_dst, att_src, att_dst, u);
  wsplit_kernel<<<L * 3, 256, 0, stream>>>(W_src, whT, wlT);
  usplit_kernel<<<dim3(L, 6), D, 0, stream>>>(u, uh, ul, L);

  const int tb = 256;
  count_kernel<<<(EN + tb - 1) / tb, tb, 0, stream>>>(e_neg_dst, cur0, EN);
  count2_kernel<<<(EC + tb - 1) / tb, tb, 0, stream>>>(e_con_src, e_con_dst, cur1, cur2, EC);

  auto pbof = [](int n) {
    int pb = ((n + 1023) / 1024 + 255) & ~255;
    return pb < 256 ? 256 : pb;
  };
  int pb0 = pbof(V), pb1 = pbof(C), pb2 = pbof(V);
  int nb0 = (V + pb0 - 1) / pb0, nb1 = (C + pb1 - 1) / pb1, nb2 = (V + pb2 - 1) / pb2;
  int nbmax = nb0 > nb1 ? nb0 : nb1; if (nb2 > nbmax) nbmax = nb2;
  bsum3_kernel<<<dim3(nbmax, 3), 256, 0, stream>>>(cur0, cur1, cur2, bsums, V, C, V, pb0, pb1, pb2);
  bscan3_kernel<<<3, 1024, 0, stream>>>(bsums, rp0 + V, rp1 + C, rp2 + V);
  scanfill3_kernel<<<dim3(nbmax, 3), 256, 0, stream>>>(cur0, cur1, cur2, bsums,
                                                       rp0, rp1, rp2, cur0, cur1, cur2,
                                                       V, C, V, pb0, pb1, pb2);

  fill_kernel<<<(EN + tb - 1) / tb, tb, 0, stream>>>(e_neg_dst, e_neg_src, cur0, col0, EN);
  fill2_kernel<<<(EC + tb - 1) / tb, tb, 0, stream>>>(e_con_src, e_con_dst, cur1, cur2, col1, col2, EC);

  auto Wh = [&](int l, int rel) { return whT + ((size_t)l * 3 + rel) * D * D; };
  auto Wl = [&](int l, int rel) { return wlT + ((size_t)l * 3 + rel) * D * D; };
  auto Bp = [&](int l, int rel) { return bias + ((size_t)l * 3 + rel) * D; };

  int gwaves = (V + C + 3) / 4;
  const int MB0 = 1024, MB1 = 2048, MB2 = 2560;

  for (int l = 0; l < L; ++l) {
    const short* uah = uh + (size_t)l * 6 * D;
    const short* ual = ul + (size_t)l * 6 * D;
    if (l == 0) {
      mm3r_kernel<float><<<MB2, 256, 0, stream>>>(
          x_var, x_con, Wh(l,0), Wl(l,0), Wh(l,1), Wl(l,1), Wh(l,2), Wl(l,2),
          uah, ual, hsv0, hsv1, hsc,
          es0, ed0, es1, ed2, es2, ed1, V, C, MB0, MB1, MB2);
    } else {
      mm3r_kernel<bf16><<<MB2, 256, 0, stream>>>(
          xv, xc, Wh(l,0), Wl(l,0), Wh(l,1), Wl(l,1), Wh(l,2), Wl(l,2),
          uah, ual, hsv0, hsv1, hsc,
          es0, ed0, es1, ed2, es2, ed1, V, C, MB0, MB1, MB2);
    }
    alpha_all_kernel<<<gwaves, 256, 0, stream>>>(
        rp0, col0, es0, ed0, eda0,
        rp2, col2, es2, ed2, eda2,
        rp1, col1, es1, ed1, eda1, V, C);
    agg_all_kernel<<<gwaves, 256, 0, stream>>>(
        rp0, eda0, hsv0, Bp(l,0),
        rp2, eda2, hsc,  Bp(l,2),
        rp1, eda1, hsv1, Bp(l,1),
        xv, xc, V, C);
  }

  pool_kernel<<<(V + 127) / 128, 128, 0, stream>>>(xv, batch_var, pooled, cntf, 128, V);
  mlp_kernel<<<1, 256, 0, stream>>>(pooled, cntf, mlp_w1, mlp_b1, mlp_w2, mlp_b2, out, B);
}

extern "C" void kernel_launch(void* const* d_in, const int* in_sizes, int n_in,
                              void* d_out, int out_size, void* d_ws, size_t ws_size,
                              hipStream_t stream) {
  const float* x_var   = (const float*)d_in[0];
  const float* x_con   = (const float*)d_in[1];
  const float* W_src   = (const float*)d_in[2];
  const float* W_dst   = (const float*)d_in[3];
  const float* att_src = (const float*)d_in[4];
  const float* att_dst = (const float*)d_in[5];
  const float* bias    = (const float*)d_in[6];
  const float* mlp_w1  = (const float*)d_in[7];
  const float* mlp_b1  = (const float*)d_in[8];
  const float* mlp_w2  = (const float*)d_in[9];
  const float* mlp_b2  = (const float*)d_in[10];
  const int* e_neg_src = (const int*)d_in[11];
  const int* e_neg_dst = (const int*)d_in[12];
  const int* e_con_src = (const int*)d_in[13];
  const int* e_con_dst = (const int*)d_in[14];
  const int* batch_var = (const int*)d_in[15];
  (void)n_in;

  const int V  = in_sizes[0] / D;
  const int C  = in_sizes[1] / D;
  const int L  = in_sizes[2] / (3 * D * D);
  const int EN = in_sizes[11];
  const int EC = in_sizes[13];
  const int B  = out_size;

  auto plan = [&]() -> size_t {
    size_t o = 0;
    auto add = [&](size_t b) { o = (o + b + 255) & ~(size_t)255; };
    add((size_t)V * D * 2); add((size_t)C * D * 2);
    add((size_t)V * D * 2); add((size_t)V * D * 2); add((size_t)C * D * 2);
    add((size_t)V * 4); add((size_t)V * 4); add((size_t)V * 4); add((size_t)V * 4);
    add((size_t)C * 4); add((size_t)C * 4);
    add((size_t)L * 3 * 2 * D * 4);
    add((size_t)L * 3 * D * D * 2); add((size_t)L * 3 * D * D * 2);
    add((size_t)L * 6 * D * 2); add((size_t)L * 6 * D * 2);
    add((size_t)(V + 1) * 4); add((size_t)(C + 1) * 4); add((size_t)(V + 1) * 4);
    add((size_t)(2 * (size_t)V + C) * 4);
    add((size_t)EN * 4); add((size_t)EC * 4); add((size_t)EC * 4);
    add((size_t)EN * 8); add((size_t)EC * 8); add((size_t)EC * 8);
    add((size_t)3 * 1024 * 4);
    add((size_t)(B * D + B) * 4);
    return o;
  };

  if (plan() <= ws_size) {
    run_all(x_var, x_con, W_src, W_dst, att_src, att_dst, bias,
            mlp_w1, mlp_b1, mlp_w2, mlp_b2,
            e_neg_src, e_neg_dst, e_con_src, e_con_dst, batch_var,
            V, C, L, EN, EC, B, (char*)d_ws, (float*)d_out, stream);
  } else {
    zero_kernel<<<(out_size + 63) / 64, 64, 0, stream>>>((float*)d_out, out_size);
  }
}

// Round 11
// 933.024 us; speedup vs baseline: 1.0449x; 1.0401x over previous
//
#include <hip/hip_runtime.h>
#include <hip/hip_bf16.h>
#include <cstdint>
#include <cstddef>

#define D 128

typedef __hip_bfloat16 bf16;
typedef __attribute__((ext_vector_type(8))) short short8v;   // 8 bf16 (4 VGPR)
typedef __attribute__((ext_vector_type(4))) float f32x4;     // MFMA 16x16 acc

// ---------- typed load/store helpers ----------
__device__ inline float ld1(const float* p) { return *p; }
__device__ inline float ld1(const bf16* p) { return __bfloat162float(*p); }
__device__ inline float2 ld2(const float* p) { return *(const float2*)p; }
__device__ inline float2 ld2(const bf16* p) {
  __hip_bfloat162 v = *(const __hip_bfloat162*)p;
  float2 r; r.x = __bfloat162float(v.x); r.y = __bfloat162float(v.y); return r;
}
__device__ inline void st2(float* p, float a, float b) {
  float2 v; v.x = a; v.y = b; *(float2*)p = v;
}
__device__ inline void st2(bf16* p, float a, float b) {
  __hip_bfloat162 v; v.x = __float2bfloat16(a); v.y = __float2bfloat16(b);
  *(__hip_bfloat162*)p = v;
}

// bf16 helpers via intrinsic casts (compiler fuses pairs into v_cvt_pk_bf16_f32)
__device__ inline short f2bf(float x) {
  bf16 h = __float2bfloat16(x);
  return *(short*)&h;
}
__device__ inline float bf2f(short s) {
  uint32_t u = ((uint32_t)(uint16_t)s) << 16;
  return __builtin_bit_cast(float, u);
}

__device__ inline f32x4 mfma16(short8v a, short8v b, f32x4 c) {
  return __builtin_amdgcn_mfma_f32_16x16x32_bf16(a, b, c, 0, 0, 0);
}

__device__ __forceinline__ void load8(const float* p, float* v) {
  float4 a = *(const float4*)p;
  float4 b = *(const float4*)(p + 4);
  v[0] = a.x; v[1] = a.y; v[2] = a.z; v[3] = a.w;
  v[4] = b.x; v[5] = b.y; v[6] = b.z; v[7] = b.w;
}

// ---------- u[l,rel,side][k] = sum_j W[l,rel,k,j] * a[l,rel,j] ----------
__global__ void compute_u_kernel(const float* __restrict__ Wsrc, const float* __restrict__ Wdst,
                                 const float* __restrict__ asrc, const float* __restrict__ adst,
                                 float* __restrict__ u) {
  int lr = blockIdx.x;
  int side = blockIdx.y;
  int k = threadIdx.x;
  const float* W = (side == 0 ? Wsrc : Wdst) + ((size_t)lr * D + k) * D;
  const float* a = (side == 0 ? asrc : adst) + (size_t)lr * D;
  float s = 0.f;
  for (int j = 0; j < D; ++j) s += W[j] * a[j];
  u[((size_t)lr * 2 + side) * D + k] = s;
}

// ---------- W split: Wh/Wl bf16, transposed [col][k] ----------
__global__ void wsplit_kernel(const float* __restrict__ Wsrc,
                              short* __restrict__ WhT, short* __restrict__ WlT) {
  int lr = blockIdx.x;
  const float* W = Wsrc + (size_t)lr * D * D;
  short* wh = WhT + (size_t)lr * D * D;
  short* wl = WlT + (size_t)lr * D * D;
  for (int i = threadIdx.x; i < D * D; i += blockDim.x) {
    int k = i >> 7, c = i & 127;
    float w = W[i];
    short h = f2bf(w);
    short l = f2bf(w - bf2f(h));
    wh[c * D + k] = h;
    wl[c * D + k] = l;
  }
}

// ---------- u split to augmented-W layout: [l][j][k], j=0..5 ----------
__global__ void usplit_kernel(const float* __restrict__ u,
                              short* __restrict__ uh, short* __restrict__ ul, int L) {
  int l = blockIdx.x;
  int j = blockIdx.y;
  int k = threadIdx.x;
  int rel, side;
  switch (j) {
    case 0: rel = 0; side = 0; break;
    case 1: rel = 0; side = 1; break;
    case 2: rel = 1; side = 0; break;
    case 3: rel = 2; side = 1; break;
    case 4: rel = 2; side = 0; break;
    default: rel = 1; side = 1; break;
  }
  float w = u[(((size_t)l * 3 + rel) * 2 + side) * D + k];
  short h = f2bf(w);
  uh[((size_t)l * 6 + j) * D + k] = h;
  ul[((size_t)l * 6 + j) * D + k] = f2bf(w - bf2f(h));
}

// ---------- CSR build ----------
__global__ void count_kernel(const int* __restrict__ dst, int* __restrict__ cnt, int E) {
  int i = blockIdx.x * blockDim.x + threadIdx.x;
  if (i < E) atomicAdd(&cnt[dst[i]], 1);
}

__global__ void count2_kernel(const int* __restrict__ csrc, const int* __restrict__ cdst,
                              int* __restrict__ cnt_bycon, int* __restrict__ cnt_byvar, int E) {
  int i = blockIdx.x * blockDim.x + threadIdx.x;
  if (i < E) {
    atomicAdd(&cnt_bycon[cdst[i]], 1);
    atomicAdd(&cnt_byvar[csrc[i]], 1);
  }
}

__global__ void bsum3_kernel(const int* __restrict__ c0, const int* __restrict__ c1,
                             const int* __restrict__ c2, int* __restrict__ bsums,
                             int n0, int n1, int n2, int pb0, int pb1, int pb2) {
  __shared__ int red[256];
  int y = blockIdx.y;
  const int* cnt = (y == 0) ? c0 : (y == 1) ? c1 : c2;
  int n  = (y == 0) ? n0 : (y == 1) ? n1 : n2;
  int pb = (y == 0) ? pb0 : (y == 1) ? pb1 : pb2;
  int b = blockIdx.x, t = threadIdx.x;
  int base = b * pb;
  if (base >= n) return;
  int end = base + pb; if (end > n) end = n;
  int s = 0;
  for (int i = base + t; i < end; i += 256) s += cnt[i];
  red[t] = s;
  __syncthreads();
  #pragma unroll
  for (int off = 128; off; off >>= 1) {
    if (t < off) red[t] += red[t + off];
    __syncthreads();
  }
  if (t == 0) bsums[y * 1024 + b] = red[0];
}

__global__ void bscan3_kernel(int* __restrict__ bsums,
                              int* __restrict__ t0, int* __restrict__ t1, int* __restrict__ t2) {
  __shared__ int sh[1024];
  int y = blockIdx.x, t = threadIdx.x;
  int* bs = bsums + y * 1024;
  int v = bs[t];
  sh[t] = v;
  __syncthreads();
  for (int off = 1; off < 1024; off <<= 1) {
    int u = (t >= off) ? sh[t - off] : 0;
    __syncthreads();
    sh[t] += u;
    __syncthreads();
  }
  bs[t] = sh[t] - v;
  if (t == 1023) {
    int* tot = (y == 0) ? t0 : (y == 1) ? t1 : t2;
    *tot = sh[1023];
  }
}

__global__ void scanfill3_kernel(const int* __restrict__ c0, const int* __restrict__ c1,
                                 const int* __restrict__ c2, const int* __restrict__ bsums,
                                 int* __restrict__ rp0, int* __restrict__ rp1, int* __restrict__ rp2,
                                 int* __restrict__ cu0, int* __restrict__ cu1, int* __restrict__ cu2,
                                 int n0, int n1, int n2, int pb0, int pb1, int pb2) {
  __shared__ int sh[256];
  int y = blockIdx.y;
  const int* cnt = (y == 0) ? c0 : (y == 1) ? c1 : c2;
  int* rowptr    = (y == 0) ? rp0 : (y == 1) ? rp1 : rp2;
  int* cursor    = (y == 0) ? cu0 : (y == 1) ? cu1 : cu2;
  int n  = (y == 0) ? n0 : (y == 1) ? n1 : n2;
  int pb = (y == 0) ? pb0 : (y == 1) ? pb1 : pb2;
  int b = blockIdx.x, t = threadIdx.x;
  int base = b * pb;
  if (base >= n) return;
  int end = base + pb; if (end > n) end = n;
  int run = bsums[y * 1024 + b];
  for (int tile = base; tile < end; tile += 256) {
    int i = tile + t;
    int c = (i < end) ? cnt[i] : 0;
    __syncthreads();
    sh[t] = c;
    __syncthreads();
    for (int off = 1; off < 256; off <<= 1) {
      int u = (t >= off) ? sh[t - off] : 0;
      __syncthreads();
      sh[t] += u;
      __syncthreads();
    }
    int excl = sh[t] - c;
    if (i < end) {
      rowptr[i] = run + excl;
      cursor[i] = run + excl;
    }
    run += sh[255];
  }
}

__global__ void fill_kernel(const int* __restrict__ dst, const int* __restrict__ src,
                            int* __restrict__ cursor, int* __restrict__ col, int E) {
  int i = blockIdx.x * blockDim.x + threadIdx.x;
  if (i < E) {
    int p = atomicAdd(&cursor[dst[i]], 1);
    col[p] = src[i];
  }
}

__global__ void fill2_kernel(const int* __restrict__ csrc, const int* __restrict__ cdst,
                             int* __restrict__ cur_bycon, int* __restrict__ cur_byvar,
                             int* __restrict__ col_bycon, int* __restrict__ col_byvar, int E) {
  int i = blockIdx.x * blockDim.x + threadIdx.x;
  if (i < E) {
    int s = csrc[i], d = cdst[i];
    int p = atomicAdd(&cur_bycon[d], 1);
    col_bycon[p] = s;
    int q = atomicAdd(&cur_byvar[s], 1);
    col_byvar[q] = d;
  }
}

// ---------- mm3v: dual-relation fused matmul (Xv read ONCE) + Xc matmul ----------
// Xv blocks: each wave holds W0 and W1 fragments (both rel), computes H0+H1+aug
// from a single X fragment. Xc blocks: single rel2. Barrier-free, prefetched.
template<typename Tin>
__global__ __launch_bounds__(256, 2) void mm3v_kernel(
    const Tin* __restrict__ Xv, const Tin* __restrict__ Xc,
    const short* __restrict__ wh0, const short* __restrict__ wl0,
    const short* __restrict__ wh1, const short* __restrict__ wl1,
    const short* __restrict__ wh2, const short* __restrict__ wl2,
    const short* __restrict__ uah, const short* __restrict__ ual,
    bf16* __restrict__ H0, bf16* __restrict__ H1, bf16* __restrict__ H2,
    float* __restrict__ es0, float* __restrict__ ed0,
    float* __restrict__ es1, float* __restrict__ ed2,
    float* __restrict__ es2, float* __restrict__ ed1,
    int V, int C, int bV, int bTot) {
  int bid = blockIdx.x;
  int tid = threadIdx.x;
  int cp = tid >> 6, lane = tid & 63;
  int c15 = lane & 15, q = lane >> 4;

  if (bid < bV) {
    // ---------- dual-relation Xv path ----------
    int nchunks = (V + 15) >> 4;
    int lb = bid, nblk = bV;
    if (lb >= nchunks) return;
    short8v W0h_[2][4], W0l_[2][4], W1h_[2][4], W1l_[2][4];
    #pragma unroll
    for (int t = 0; t < 2; ++t) {
      #pragma unroll
      for (int ks = 0; ks < 4; ++ks) {
        int o = (cp * 32 + t * 16 + c15) * D + ks * 32 + q * 8;
        W0h_[t][ks] = *(const short8v*)&wh0[o];
        W0l_[t][ks] = *(const short8v*)&wl0[o];
        W1h_[t][ks] = *(const short8v*)&wh1[o];
        W1l_[t][ks] = *(const short8v*)&wl1[o];
      }
    }
    bool doaug = (cp == 0);
    short8v Uh_[4], Ul_[4];
    if (doaug) {
      #pragma unroll
      for (int ks = 0; ks < 4; ++ks) {
        if (c15 < 4) {
          int o = c15 * D + ks * 32 + q * 8;
          Uh_[ks] = *(const short8v*)&uah[o];
          Ul_[ks] = *(const short8v*)&ual[o];
        } else {
          Uh_[ks] = (short8v){0, 0, 0, 0, 0, 0, 0, 0};
          Ul_[ks] = (short8v){0, 0, 0, 0, 0, 0, 0, 0};
        }
      }
    }

    if constexpr (sizeof(Tin) == 2) {
      auto xaddr = [&](int ch) -> const short* {
        int row = ch * 16 + c15;
        if (row >= V) row = V - 1;
        return (const short*)Xv + (size_t)row * D + q * 8;
      };
      short8v xf[4];
      {
        const short* xp = xaddr(lb);
        #pragma unroll
        for (int ks = 0; ks < 4; ++ks) xf[ks] = *(const short8v*)(xp + ks * 32);
      }
      for (int ch = lb; ch < nchunks; ch += nblk) {
        int nch = ch + nblk;
        short8v xn[4];
        if (nch < nchunks) {
          const short* xp = xaddr(nch);
          #pragma unroll
          for (int ks = 0; ks < 4; ++ks) xn[ks] = *(const short8v*)(xp + ks * 32);
        }
        f32x4 a00 = (f32x4){0.f, 0.f, 0.f, 0.f};
        f32x4 a01 = (f32x4){0.f, 0.f, 0.f, 0.f};
        f32x4 a10 = (f32x4){0.f, 0.f, 0.f, 0.f};
        f32x4 a11 = (f32x4){0.f, 0.f, 0.f, 0.f};
        f32x4 a2  = (f32x4){0.f, 0.f, 0.f, 0.f};
        #pragma unroll
        for (int ks = 0; ks < 4; ++ks) {
          a00 = mfma16(W0h_[0][ks], xf[ks], a00);
          a00 = mfma16(W0l_[0][ks], xf[ks], a00);
          a01 = mfma16(W0h_[1][ks], xf[ks], a01);
          a01 = mfma16(W0l_[1][ks], xf[ks], a01);
          a10 = mfma16(W1h_[0][ks], xf[ks], a10);
          a10 = mfma16(W1l_[0][ks], xf[ks], a10);
          a11 = mfma16(W1h_[1][ks], xf[ks], a11);
          a11 = mfma16(W1l_[1][ks], xf[ks], a11);
          if (doaug) {
            a2 = mfma16(Uh_[ks], xf[ks], a2);
            a2 = mfma16(Ul_[ks], xf[ks], a2);
          }
        }
        int row = ch * 16 + c15;
        if (row < V) {
          short4 s0, s1, s2, s3;
          s0.x = f2bf(a00[0]); s0.y = f2bf(a00[1]); s0.z = f2bf(a00[2]); s0.w = f2bf(a00[3]);
          s1.x = f2bf(a01[0]); s1.y = f2bf(a01[1]); s1.z = f2bf(a01[2]); s1.w = f2bf(a01[3]);
          s2.x = f2bf(a10[0]); s2.y = f2bf(a10[1]); s2.z = f2bf(a10[2]); s2.w = f2bf(a10[3]);
          s3.x = f2bf(a11[0]); s3.y = f2bf(a11[1]); s3.z = f2bf(a11[2]); s3.w = f2bf(a11[3]);
          size_t hb = (size_t)row * D + cp * 32 + q * 4;
          *(short4*)((short*)H0 + hb) = s0;
          *(short4*)((short*)H0 + hb + 16) = s1;
          *(short4*)((short*)H1 + hb) = s2;
          *(short4*)((short*)H1 + hb + 16) = s3;
          if (doaug && q == 0) {
            es0[row] = a2[0];
            ed0[row] = a2[1];
            es1[row] = a2[2];
            ed2[row] = a2[3];
          }
        }
        #pragma unroll
        for (int ks = 0; ks < 4; ++ks) xf[ks] = xn[ks];
      }
    } else {
      // fp32 layer-0: register split-bf16, 3-term per (rel, tile)
      for (int ch = lb; ch < nchunks; ch += nblk) {
        int row = ch * 16 + c15;
        bool valid = row < V;
        if (!valid) row = V - 1;
        const Tin* xp = Xv + (size_t)row * D + q * 8;
        short8v xh[4], xl[4];
        #pragma unroll
        for (int ks = 0; ks < 4; ++ks) {
          float v[8];
          load8((const float*)xp + ks * 32, v);
          #pragma unroll
          for (int j = 0; j < 8; ++j) {
            short hj = f2bf(v[j]);
            xh[ks][j] = hj;
            xl[ks][j] = f2bf(v[j] - bf2f(hj));
          }
        }
        f32x4 a00 = (f32x4){0.f, 0.f, 0.f, 0.f};
        f32x4 a01 = (f32x4){0.f, 0.f, 0.f, 0.f};
        f32x4 a10 = (f32x4){0.f, 0.f, 0.f, 0.f};
        f32x4 a11 = (f32x4){0.f, 0.f, 0.f, 0.f};
        f32x4 a2  = (f32x4){0.f, 0.f, 0.f, 0.f};
        #pragma unroll
        for (int ks = 0; ks < 4; ++ks) {
          a00 = mfma16(W0h_[0][ks], xh[ks], a00);
          a00 = mfma16(W0l_[0][ks], xh[ks], a00);
          a00 = mfma16(W0h_[0][ks], xl[ks], a00);
          a01 = mfma16(W0h_[1][ks], xh[ks], a01);
          a01 = mfma16(W0l_[1][ks], xh[ks], a01);
          a01 = mfma16(W0h_[1][ks], xl[ks], a01);
          a10 = mfma16(W1h_[0][ks], xh[ks], a10);
          a10 = mfma16(W1l_[0][ks], xh[ks], a10);
          a10 = mfma16(W1h_[0][ks], xl[ks], a10);
          a11 = mfma16(W1h_[1][ks], xh[ks], a11);
          a11 = mfma16(W1l_[1][ks], xh[ks], a11);
          a11 = mfma16(W1h_[1][ks], xl[ks], a11);
          if (doaug) {
            a2 = mfma16(Uh_[ks], xh[ks], a2);
            a2 = mfma16(Ul_[ks], xh[ks], a2);
            a2 = mfma16(Uh_[ks], xl[ks], a2);
          }
        }
        if (valid) {
          short4 s0, s1, s2, s3;
          s0.x = f2bf(a00[0]); s0.y = f2bf(a00[1]); s0.z = f2bf(a00[2]); s0.w = f2bf(a00[3]);
          s1.x = f2bf(a01[0]); s1.y = f2bf(a01[1]); s1.z = f2bf(a01[2]); s1.w = f2bf(a01[3]);
          s2.x = f2bf(a10[0]); s2.y = f2bf(a10[1]); s2.z = f2bf(a10[2]); s2.w = f2bf(a10[3]);
          s3.x = f2bf(a11[0]); s3.y = f2bf(a11[1]); s3.z = f2bf(a11[2]); s3.w = f2bf(a11[3]);
          size_t hb = (size_t)row * D + cp * 32 + q * 4;
          *(short4*)((short*)H0 + hb) = s0;
          *(short4*)((short*)H0 + hb + 16) = s1;
          *(short4*)((short*)H1 + hb) = s2;
          *(short4*)((short*)H1 + hb + 16) = s3;
          if (doaug && q == 0) {
            es0[row] = a2[0];
            ed0[row] = a2[1];
            es1[row] = a2[2];
            ed2[row] = a2[3];
          }
        }
      }
    }
  } else {
    // ---------- single-relation Xc path ----------
    int nchunks = (C + 15) >> 4;
    int lb = bid - bV, nblk = bTot - bV;
    if (lb >= nchunks) return;
    short8v Wh_[2][4], Wl_[2][4];
    #pragma unroll
    for (int t = 0; t < 2; ++t) {
      #pragma unroll
      for (int ks = 0; ks < 4; ++ks) {
        int o = (cp * 32 + t * 16 + c15) * D + ks * 32 + q * 8;
        Wh_[t][ks] = *(const short8v*)&wh2[o];
        Wl_[t][ks] = *(const short8v*)&wl2[o];
      }
    }
    bool doaug = (cp == 0);
    const short* auh = uah + 4 * D;
    const short* aul = ual + 4 * D;
    short8v Uh_[4], Ul_[4];
    if (doaug) {
      #pragma unroll
      for (int ks = 0; ks < 4; ++ks) {
        if (c15 < 2) {
          int o = c15 * D + ks * 32 + q * 8;
          Uh_[ks] = *(const short8v*)&auh[o];
          Ul_[ks] = *(const short8v*)&aul[o];
        } else {
          Uh_[ks] = (short8v){0, 0, 0, 0, 0, 0, 0, 0};
          Ul_[ks] = (short8v){0, 0, 0, 0, 0, 0, 0, 0};
        }
      }
    }

    if constexpr (sizeof(Tin) == 2) {
      auto xaddr = [&](int ch) -> const short* {
        int row = ch * 16 + c15;
        if (row >= C) row = C - 1;
        return (const short*)Xc + (size_t)row * D + q * 8;
      };
      short8v xf[4];
      {
        const short* xp = xaddr(lb);
        #pragma unroll
        for (int ks = 0; ks < 4; ++ks) xf[ks] = *(const short8v*)(xp + ks * 32);
      }
      for (int ch = lb; ch < nchunks; ch += nblk) {
        int nch = ch + nblk;
        short8v xn[4];
        if (nch < nchunks) {
          const short* xp = xaddr(nch);
          #pragma unroll
          for (int ks = 0; ks < 4; ++ks) xn[ks] = *(const short8v*)(xp + ks * 32);
        }
        f32x4 a0 = (f32x4){0.f, 0.f, 0.f, 0.f};
        f32x4 a1 = (f32x4){0.f, 0.f, 0.f, 0.f};
        f32x4 a2 = (f32x4){0.f, 0.f, 0.f, 0.f};
        #pragma unroll
        for (int ks = 0; ks < 4; ++ks) {
          a0 = mfma16(Wh_[0][ks], xf[ks], a0);
          a0 = mfma16(Wl_[0][ks], xf[ks], a0);
          a1 = mfma16(Wh_[1][ks], xf[ks], a1);
          a1 = mfma16(Wl_[1][ks], xf[ks], a1);
          if (doaug) {
            a2 = mfma16(Uh_[ks], xf[ks], a2);
            a2 = mfma16(Ul_[ks], xf[ks], a2);
          }
        }
        int row = ch * 16 + c15;
        if (row < C) {
          short4 s0, s1;
          s0.x = f2bf(a0[0]); s0.y = f2bf(a0[1]); s0.z = f2bf(a0[2]); s0.w = f2bf(a0[3]);
          s1.x = f2bf(a1[0]); s1.y = f2bf(a1[1]); s1.z = f2bf(a1[2]); s1.w = f2bf(a1[3]);
          size_t hb = (size_t)row * D + cp * 32 + q * 4;
          *(short4*)((short*)H2 + hb) = s0;
          *(short4*)((short*)H2 + hb + 16) = s1;
          if (doaug && q == 0) {
            es2[row] = a2[0];
            ed1[row] = a2[1];
          }
        }
        #pragma unroll
        for (int ks = 0; ks < 4; ++ks) xf[ks] = xn[ks];
      }
    } else {
      for (int ch = lb; ch < nchunks; ch += nblk) {
        int row = ch * 16 + c15;
        bool valid = row < C;
        if (!valid) row = C - 1;
        const Tin* xp = Xc + (size_t)row * D + q * 8;
        short8v xh[4], xl[4];
        #pragma unroll
        for (int ks = 0; ks < 4; ++ks) {
          float v[8];
          load8((const float*)xp + ks * 32, v);
          #pragma unroll
          for (int j = 0; j < 8; ++j) {
            short hj = f2bf(v[j]);
            xh[ks][j] = hj;
            xl[ks][j] = f2bf(v[j] - bf2f(hj));
          }
        }
        f32x4 a0 = (f32x4){0.f, 0.f, 0.f, 0.f};
        f32x4 a1 = (f32x4){0.f, 0.f, 0.f, 0.f};
        f32x4 a2 = (f32x4){0.f, 0.f, 0.f, 0.f};
        #pragma unroll
        for (int ks = 0; ks < 4; ++ks) {
          a0 = mfma16(Wh_[0][ks], xh[ks], a0);
          a0 = mfma16(Wl_[0][ks], xh[ks], a0);
          a0 = mfma16(Wh_[0][ks], xl[ks], a0);
          a1 = mfma16(Wh_[1][ks], xh[ks], a1);
          a1 = mfma16(Wl_[1][ks], xh[ks], a1);
          a1 = mfma16(Wh_[1][ks], xl[ks], a1);
          if (doaug) {
            a2 = mfma16(Uh_[ks], xh[ks], a2);
            a2 = mfma16(Ul_[ks], xh[ks], a2);
            a2 = mfma16(Uh_[ks], xl[ks], a2);
          }
        }
        if (valid) {
          short4 s0, s1;
          s0.x = f2bf(a0[0]); s0.y = f2bf(a0[1]); s0.z = f2bf(a0[2]); s0.w = f2bf(a0[3]);
          s1.x = f2bf(a1[0]); s1.y = f2bf(a1[1]); s1.z = f2bf(a1[2]); s1.w = f2bf(a1[3]);
          size_t hb = (size_t)row * D + cp * 32 + q * 4;
          *(short4*)((short*)H2 + hb) = s0;
          *(short4*)((short*)H2 + hb + 16) = s1;
          if (doaug && q == 0) {
            es2[row] = a2[0];
            ed1[row] = a2[1];
          }
        }
      }
    }
  }
}

// ---------- alpha pass: per-dst softmax -> CSR-ordered (src, alpha) pairs ----------
__device__ __forceinline__ void alpha_rel(const int* __restrict__ rp, const int* __restrict__ col,
                                          const float* __restrict__ es, float edst,
                                          int gw, int lane, int2* __restrict__ edata) {
  int p0 = rp[gw];
  int deg = rp[gw + 1] - p0;
  if (deg <= 0) return;
  if (deg <= 64) {
    int s = 0; float e = -3.0e38f;
    if (lane < deg) {
      s = col[p0 + lane];
      float t = es[s] + edst;
      e = t > 0.f ? t : 0.2f * t;
    }
    float m = e;
    #pragma unroll
    for (int off = 32; off; off >>= 1) m = fmaxf(m, __shfl_xor(m, off));
    float ex = (lane < deg) ? __expf(e - m) : 0.f;
    float den = ex;
    #pragma unroll
    for (int off = 32; off; off >>= 1) den += __shfl_xor(den, off);
    float al = ex / (den + 1e-16f);
    if (lane < deg) {
      int2 v; v.x = s; v.y = __builtin_bit_cast(int, al);
      edata[p0 + lane] = v;
    }
  } else {
    float m = -3.0e38f;
    for (int j = lane; j < deg; j += 64) {
      int s = col[p0 + j];
      float t = es[s] + edst;
      t = t > 0.f ? t : 0.2f * t;
      m = fmaxf(m, t);
    }
    #pragma unroll
    for (int off = 32; off; off >>= 1) m = fmaxf(m, __shfl_xor(m, off));
    float den = 0.f;
    for (int j = lane; j < deg; j += 64) {
      int s = col[p0 + j];
      float t = es[s] + edst;
      t = t > 0.f ? t : 0.2f * t;
      den += __expf(t - m);
    }
    #pragma unroll
    for (int off = 32; off; off >>= 1) den += __shfl_xor(den, off);
    float inv = 1.f / (den + 1e-16f);
    for (int j = lane; j < deg; j += 64) {
      int s = col[p0 + j];
      float t = es[s] + edst;
      t = t > 0.f ? t : 0.2f * t;
      int2 v; v.x = s; v.y = __builtin_bit_cast(int, __expf(t - m) * inv);
      edata[p0 + j] = v;
    }
  }
}

__global__ void alpha_all_kernel(const int* __restrict__ rp0, const int* __restrict__ col0,
                                 const float* __restrict__ es0, const float* __restrict__ ed0,
                                 int2* __restrict__ eda0,
                                 const int* __restrict__ rp2, const int* __restrict__ col2,
                                 const float* __restrict__ es2, const float* __restrict__ ed2,
                                 int2* __restrict__ eda2,
                                 const int* __restrict__ rp1, const int* __restrict__ col1,
                                 const float* __restrict__ es1, const float* __restrict__ ed1,
                                 int2* __restrict__ eda1,
                                 int V, int C) {
  int gw = (int)(((size_t)blockIdx.x * blockDim.x + threadIdx.x) >> 6);
  int lane = threadIdx.x & 63;
  if (gw < V) {
    alpha_rel(rp0, col0, es0, ed0[gw], gw, lane, eda0);
    alpha_rel(rp2, col2, es2, ed2[gw], gw, lane, eda2);
  } else if (gw < V + C) {
    int g = gw - V;
    alpha_rel(rp1, col1, es1, ed1[g], g, lane, eda1);
  }
}

// ---------- gather pass: half-wave scheme, 2 edges per wave, 8 B/lane ----------
__device__ __forceinline__ void gload4(const bf16* p, float* h) {
  short4 s = *(const short4*)p;
  h[0] = bf2f(s.x); h[1] = bf2f(s.y); h[2] = bf2f(s.z); h[3] = bf2f(s.w);
}

__device__ __forceinline__ void agg_rel2(const int2* __restrict__ edata, int p0, int p1,
                                         const bf16* __restrict__ hs, int c4, int half,
                                         float* a) {
  int q = p0 + half;
  while (q + 6 < p1) {
    int2 e0 = edata[q], e1 = edata[q + 2], e2 = edata[q + 4], e3 = edata[q + 6];
    float h0[4], h1[4], h2[4], h3[4];
    gload4(&hs[(size_t)e0.x * D + c4], h0);
    gload4(&hs[(size_t)e1.x * D + c4], h1);
    gload4(&hs[(size_t)e2.x * D + c4], h2);
    gload4(&hs[(size_t)e3.x * D + c4], h3);
    float w0 = __builtin_bit_cast(float, e0.y);
    float w1 = __builtin_bit_cast(float, e1.y);
    float w2 = __builtin_bit_cast(float, e2.y);
    float w3 = __builtin_bit_cast(float, e3.y);
    #pragma unroll
    for (int j = 0; j < 4; ++j)
      a[j] += w0 * h0[j] + w1 * h1[j] + w2 * h2[j] + w3 * h3[j];
    q += 8;
  }
  while (q < p1) {
    int2 e = edata[q];
    float h[4];
    gload4(&hs[(size_t)e.x * D + c4], h);
    float w = __builtin_bit_cast(float, e.y);
    #pragma unroll
    for (int j = 0; j < 4; ++j) a[j] += w * h[j];
    q += 2;
  }
}

__global__ void agg_all_kernel(const int* __restrict__ rp0, const int2* __restrict__ eda0,
                               const bf16* __restrict__ hsv0, const float* __restrict__ b0,
                               const int* __restrict__ rp2, const int2* __restrict__ eda2,
                               const bf16* __restrict__ hsc, const float* __restrict__ b2,
                               const int* __restrict__ rp1, const int2* __restrict__ eda1,
                               const bf16* __restrict__ hsv1, const float* __restrict__ b1,
                               bf16* __restrict__ xv_out, bf16* __restrict__ xc_out, int V, int C) {
  int gw = (int)(((size_t)blockIdx.x * blockDim.x + threadIdx.x) >> 6);
  int lane = threadIdx.x & 63;
  int half = lane >> 5;
  int c4 = (lane & 31) * 4;
  float a[4] = {0.f, 0.f, 0.f, 0.f};
  if (gw < V) {
    agg_rel2(eda0, rp0[gw], rp0[gw + 1], hsv0, c4, half, a);
    agg_rel2(eda2, rp2[gw], rp2[gw + 1], hsc, c4, half, a);
    #pragma unroll
    for (int j = 0; j < 4; ++j) a[j] += __shfl_xor(a[j], 32);
    if (half == 0) {
      float4 ba = *(const float4*)&b0[c4];
      float4 bb = *(const float4*)&b2[c4];
      float v0 = a[0] + ba.x + bb.x, v1 = a[1] + ba.y + bb.y;
      float v2 = a[2] + ba.z + bb.z, v3 = a[3] + ba.w + bb.w;
      short4 o;
      o.x = f2bf(v0 > 0.f ? v0 : 0.f);
      o.y = f2bf(v1 > 0.f ? v1 : 0.f);
      o.z = f2bf(v2 > 0.f ? v2 : 0.f);
      o.w = f2bf(v3 > 0.f ? v3 : 0.f);
      *(short4*)((short*)xv_out + (size_t)gw * D + c4) = o;
    }
  } else if (gw < V + C) {
    int g = gw - V;
    agg_rel2(eda1, rp1[g], rp1[g + 1], hsv1, c4, half, a);
    #pragma unroll
    for (int j = 0; j < 4; ++j) a[j] += __shfl_xor(a[j], 32);
    if (half == 0) {
      float4 ba = *(const float4*)&b1[c4];
      float v0 = a[0] + ba.x, v1 = a[1] + ba.y;
      float v2 = a[2] + ba.z, v3 = a[3] + ba.w;
      short4 o;
      o.x = f2bf(v0 > 0.f ? v0 : 0.f);
      o.y = f2bf(v1 > 0.f ? v1 : 0.f);
      o.z = f2bf(v2 > 0.f ? v2 : 0.f);
      o.w = f2bf(v3 > 0.f ? v3 : 0.f);
      *(short4*)((short*)xc_out + (size_t)g * D + c4) = o;
    }
  }
}

// ---------- pooling over sorted batch ids ----------
__global__ void pool_kernel(const bf16* __restrict__ xv, const int* __restrict__ batch,
                            float* __restrict__ pooled, float* __restrict__ cntf,
                            int rowsPerBlock, int V) {
  int j = threadIdx.x;
  int r0 = blockIdx.x * rowsPerBlock;
  if (r0 >= V) return;
  int rend = r0 + rowsPerBlock; if (rend > V) rend = V;
  int cur = batch[r0];
  float s = 0.f;
  int run = 0;
  for (int r = r0; r < rend; ++r) {
    int b = batch[r];
    if (b != cur) {
      atomicAdd(&pooled[(size_t)cur * D + j], s);
      if (j == 0) atomicAdd(&cntf[cur], (float)run);
      s = 0.f; run = 0; cur = b;
    }
    s += ld1(&xv[(size_t)r * D + j]);
    run++;
  }
  atomicAdd(&pooled[(size_t)cur * D + j], s);
  if (j == 0) atomicAdd(&cntf[cur], (float)run);
}

// ---------- final MLP ----------
__global__ void mlp_kernel(const float* __restrict__ pooled, const float* __restrict__ cntf,
                           const float* __restrict__ w1, const float* __restrict__ b1,
                           const float* __restrict__ w2, const float* __restrict__ b2,
                           float* __restrict__ out, int B) {
  __shared__ float P[32 * D];
  __shared__ float Hs[32 * D];
  int tid = threadIdx.x;
  if (B > 32) return;
  for (int i = tid; i < B * D; i += 256) {
    int r = i >> 7;
    P[i] = pooled[i] / fmaxf(cntf[r], 1.0f);
  }
  __syncthreads();
  for (int i = tid; i < B * D; i += 256) {
    int r = i >> 7, j = i & 127;
    float s = b1[j];
    for (int k = 0; k < D; ++k) s += P[r * D + k] * w1[k * D + j];
    Hs[i] = s > 0.f ? s : 0.f;
  }
  __syncthreads();
  if (tid < B) {
    float s = b2[0];
    for (int j = 0; j < D; ++j) s += Hs[tid * D + j] * w2[j];
    out[tid] = s;
  }
}

__global__ void zero_kernel(float* __restrict__ o, int n) {
  int i = blockIdx.x * blockDim.x + threadIdx.x;
  if (i < n) o[i] = 0.f;
}

// ---------- full pipeline (features stored bf16, compute fp32) ----------
static void run_all(const float* x_var, const float* x_con,
                    const float* W_src, const float* W_dst,
                    const float* att_src, const float* att_dst, const float* bias,
                    const float* mlp_w1, const float* mlp_b1,
                    const float* mlp_w2, const float* mlp_b2,
                    const int* e_neg_src, const int* e_neg_dst,
                    const int* e_con_src, const int* e_con_dst, const int* batch_var,
                    int V, int C, int L, int EN, int EC, int B,
                    char* ws, float* out, hipStream_t stream) {
  size_t off = 0;
  auto alloc = [&](size_t bytes) -> char* {
    char* p = ws + off;
    off = (off + bytes + 255) & ~(size_t)255;
    return p;
  };
  bf16* xv  = (bf16*)alloc((size_t)V * D * 2);
  bf16* xc  = (bf16*)alloc((size_t)C * D * 2);
  bf16* hsv0 = (bf16*)alloc((size_t)V * D * 2);
  bf16* hsv1 = (bf16*)alloc((size_t)V * D * 2);
  bf16* hsc  = (bf16*)alloc((size_t)C * D * 2);
  float* es0 = (float*)alloc((size_t)V * 4);
  float* ed0 = (float*)alloc((size_t)V * 4);
  float* es1 = (float*)alloc((size_t)V * 4);
  float* ed2 = (float*)alloc((size_t)V * 4);
  float* es2 = (float*)alloc((size_t)C * 4);
  float* ed1 = (float*)alloc((size_t)C * 4);
  float* u   = (float*)alloc((size_t)L * 3 * 2 * D * 4);
  short* whT = (short*)alloc((size_t)L * 3 * D * D * 2);
  short* wlT = (short*)alloc((size_t)L * 3 * D * D * 2);
  short* uh  = (short*)alloc((size_t)L * 6 * D * 2);
  short* ul  = (short*)alloc((size_t)L * 6 * D * 2);
  int* rp0  = (int*)alloc((size_t)(V + 1) * 4);
  int* rp1  = (int*)alloc((size_t)(C + 1) * 4);
  int* rp2  = (int*)alloc((size_t)(V + 1) * 4);
  int* curs = (int*)alloc((size_t)(2 * (size_t)V + C) * 4);
  int* cur0 = curs, *cur1 = curs + V, *cur2 = curs + V + C;
  int* col0 = (int*)alloc((size_t)EN * 4);
  int* col1 = (int*)alloc((size_t)EC * 4);
  int* col2 = (int*)alloc((size_t)EC * 4);
  int2* eda0 = (int2*)alloc((size_t)EN * 8);
  int2* eda1 = (int2*)alloc((size_t)EC * 8);
  int2* eda2 = (int2*)alloc((size_t)EC * 8);
  int* bsums = (int*)alloc((size_t)3 * 1024 * 4);
  float* pooled = (float*)alloc((size_t)(B * D + B) * 4);
  float* cntf = pooled + (size_t)B * D;

  hipMemsetAsync(curs, 0, (size_t)(2 * (size_t)V + C) * 4, stream);
  hipMemsetAsync(bsums, 0, (size_t)3 * 1024 * 4, stream);
  hipMemsetAsync(pooled, 0, (size_t)(B * D + B) * 4, stream);

  compute_u_kernel<<<dim3(L * 3, 2), D, 0, stream>>>(W_src, W_dst, att_src, att_dst, u);
  wsplit_kernel<<<L * 3, 256, 0, stream>>>(W_src, whT, wlT);
  usplit_kernel<<<dim3(L, 6), D, 0, stream>>>(u, uh, ul, L);

  const int tb = 256;
  count_kernel<<<(EN + tb - 1) / tb, tb, 0, stream>>>(e_neg_dst, cur0, EN);
  count2_kernel<<<(EC + tb - 1) / tb, tb, 0, stream>>>(e_con_src, e_con_dst, cur1, cur2, EC);

  auto pbof = [](int n) {
    int pb = ((n + 1023) / 1024 + 255) & ~255;
    return pb < 256 ? 256 : pb;
  };
  int pb0 = pbof(V), pb1 = pbof(C), pb2 = pbof(V);
  int nb0 = (V + pb0 - 1) / pb0, nb1 = (C + pb1 - 1) / pb1, nb2 = (V + pb2 - 1) / pb2;
  int nbmax = nb0 > nb1 ? nb0 : nb1; if (nb2 > nbmax) nbmax = nb2;
  bsum3_kernel<<<dim3(nbmax, 3), 256, 0, stream>>>(cur0, cur1, cur2, bsums, V, C, V, pb0, pb1, pb2);
  bscan3_kernel<<<3, 1024, 0, stream>>>(bsums, rp0 + V, rp1 + C, rp2 + V);
  scanfill3_kernel<<<dim3(nbmax, 3), 256, 0, stream>>>(cur0, cur1, cur2, bsums,
                                                       rp0, rp1, rp2, cur0, cur1, cur2,
                                                       V, C, V, pb0, pb1, pb2);

  fill_kernel<<<(EN + tb - 1) / tb, tb, 0, stream>>>(e_neg_dst, e_neg_src, cur0, col0, EN);
  fill2_kernel<<<(EC + tb - 1) / tb, tb, 0, stream>>>(e_con_src, e_con_dst, cur1, cur2, col1, col2, EC);

  auto Wh = [&](int l, int rel) { return whT + ((size_t)l * 3 + rel) * D * D; };
  auto Wl = [&](int l, int rel) { return wlT + ((size_t)l * 3 + rel) * D * D; };
  auto Bp = [&](int l, int rel) { return bias + ((size_t)l * 3 + rel) * D; };

  int gwaves = (V + C + 3) / 4;
  const int MBV = 1024, MBT = 1280;   // 1024 dual-Xv blocks + 256 Xc blocks

  for (int l = 0; l < L; ++l) {
    const short* uah = uh + (size_t)l * 6 * D;
    const short* ual = ul + (size_t)l * 6 * D;
    if (l == 0) {
      mm3v_kernel<float><<<MBT, 256, 0, stream>>>(
          x_var, x_con, Wh(l,0), Wl(l,0), Wh(l,1), Wl(l,1), Wh(l,2), Wl(l,2),
          uah, ual, hsv0, hsv1, hsc,
          es0, ed0, es1, ed2, es2, ed1, V, C, MBV, MBT);
    } else {
      mm3v_kernel<bf16><<<MBT, 256, 0, stream>>>(
          xv, xc, Wh(l,0), Wl(l,0), Wh(l,1), Wl(l,1), Wh(l,2), Wl(l,2),
          uah, ual, hsv0, hsv1, hsc,
          es0, ed0, es1, ed2, es2, ed1, V, C, MBV, MBT);
    }
    alpha_all_kernel<<<gwaves, 256, 0, stream>>>(
        rp0, col0, es0, ed0, eda0,
        rp2, col2, es2, ed2, eda2,
        rp1, col1, es1, ed1, eda1, V, C);
    agg_all_kernel<<<gwaves, 256, 0, stream>>>(
        rp0, eda0, hsv0, Bp(l,0),
        rp2, eda2, hsc,  Bp(l,2),
        rp1, eda1, hsv1, Bp(l,1),
        xv, xc, V, C);
  }

  pool_kernel<<<(V + 127) / 128, 128, 0, stream>>>(xv, batch_var, pooled, cntf, 128, V);
  mlp_kernel<<<1, 256, 0, stream>>>(pooled, cntf, mlp_w1, mlp_b1, mlp_w2, mlp_b2, out, B);
}

extern "C" void kernel_launch(void* const* d_in, const int* in_sizes, int n_in,
                              void* d_out, int out_size, void* d_ws, size_t ws_size,
                              hipStream_t stream) {
  const float* x_var   = (const float*)d_in[0];
  const float* x_con   = (const float*)d_in[1];
  const float* W_src   = (const float*)d_in[2];
  const float* W_dst   = (const float*)d_in[3];
  const float* att_src = (const float*)d_in[4];
  const float* att_dst = (const float*)d_in[5];
  const float* bias    = (const float*)d_in[6];
  const float* mlp_w1  = (const float*)d_in[7];
  const float* mlp_b1  = (const float*)d_in[8];
  const float* mlp_w2  = (const float*)d_in[9];
  const float* mlp_b2  = (const float*)d_in[10];
  const int* e_neg_src = (const int*)d_in[11];
  const int* e_neg_dst = (const int*)d_in[12];
  const int* e_con_src = (const int*)d_in[13];
  const int* e_con_dst = (const int*)d_in[14];
  const int* batch_var = (const int*)d_in[15];
  (void)n_in;

  const int V  = in_sizes[0] / D;
  const int C  = in_sizes[1] / D;
  const int L  = in_sizes[2] / (3 * D * D);
  const int EN = in_sizes[11];
  const int EC = in_sizes[13];
  const int B  = out_size;

  auto plan = [&]() -> size_t {
    size_t o = 0;
    auto add = [&](size_t b) { o = (o + b + 255) & ~(size_t)255; };
    add((size_t)V * D * 2); add((size_t)C * D * 2);
    add((size_t)V * D * 2); add((size_t)V * D * 2); add((size_t)C * D * 2);
    add((size_t)V * 4); add((size_t)V * 4); add((size_t)V * 4); add((size_t)V * 4);
    add((size_t)C * 4); add((size_t)C * 4);
    add((size_t)L * 3 * 2 * D * 4);
    add((size_t)L * 3 * D * D * 2); add((size_t)L * 3 * D * D * 2);
    add((size_t)L * 6 * D * 2); add((size_t)L * 6 * D * 2);
    add((size_t)(V + 1) * 4); add((size_t)(C + 1) * 4); add((size_t)(V + 1) * 4);
    add((size_t)(2 * (size_t)V + C) * 4);
    add((size_t)EN * 4); add((size_t)EC * 4); add((size_t)EC * 4);
    add((size_t)EN * 8); add((size_t)EC * 8); add((size_t)EC * 8);
    add((size_t)3 * 1024 * 4);
    add((size_t)(B * D + B) * 4);
    return o;
  };

  if (plan() <= ws_size) {
    run_all(x_var, x_con, W_src, W_dst, att_src, att_dst, bias,
            mlp_w1, mlp_b1, mlp_w2, mlp_b2,
            e_neg_src, e_neg_dst, e_con_src, e_con_dst, batch_var,
            V, C, L, EN, EC, B, (char*)d_ws, (float*)d_out, stream);
  } else {
    zero_kernel<<<(out_size + 63) / 64, 64, 0, stream>>>((float*)d_out, out_size);
  }
}